// Round 17
// baseline (155.990 us; speedup 1.0000x reference)
//
#include <hip/hip_runtime.h>
#include <math.h>

// Problem constants (B,L,D,H,K) = (8, 2048, 1024, 16, 31)
#define BB 8
#define LL 2048
#define DD 1024
#define HH 16
#define DH 64          // D/H
#define KK 31
#define NSEG 32
#define SEGLEN 64      // LL/NSEG

#define TLEN 64        // tokens per conv block
#define TROW 2080      // avgT row stride (u16): 32-zero prefix + 2048 tokens
#define TSTR2 112      // winT row stride (u16): 14 chunks of 16B
#define WBSTR2 104     // wband row stride (u16): 208B
#define WPESTR2 72     // wpeT row stride (u16): 144B
#define PCSS 64        // pcs row stride (u16): row-internal accesses only

typedef __attribute__((ext_vector_type(8))) short bf16x8;
typedef __attribute__((ext_vector_type(4))) float f32x4;
typedef __attribute__((ext_vector_type(8))) unsigned short u16x8;

__device__ __forceinline__ unsigned short f2bf(float f) {
    unsigned u = __float_as_uint(f);
    unsigned r = (u + 0x7fffu + ((u >> 16) & 1u)) >> 16;   // RNE
    return (unsigned short)r;
}
__device__ __forceinline__ float bf2f(unsigned short s) {
    return __uint_as_float(((unsigned)s) << 16);
}

__device__ __forceinline__ void gload_lds16(const void* g, void* l) {
    __builtin_amdgcn_global_load_lds(
        (const __attribute__((address_space(1))) void*)g,
        (__attribute__((address_space(3))) void*)l, 16, 0, 0);
}

// ---------------- Pass 1a: per-segment sums (for parallel cumsum) ----------
__global__ __launch_bounds__(256)
void seg_sum_kernel(const float* __restrict__ x, float* __restrict__ segsum) {
    int g = blockIdx.x * 256 + threadIdx.x;   // B*NSEG*D threads
    int d = g & (DD - 1);
    int s = (g >> 10) & (NSEG - 1);
    int b = g >> 15;
    const float* p = x + (size_t)(b * LL + s * SEGLEN) * DD + d;
    float acc = 0.f;
    #pragma unroll 8
    for (int i = 0; i < SEGLEN; ++i) acc += p[(size_t)i * DD];
    segsum[g] = acc;   // layout [b][s][d] == flat g
}

// ---- Pass 1b: running mean -> avgT [b,h,d][32zero|2048] only --------------
__global__ __launch_bounds__(256)
void avg_kernel(const float* __restrict__ x, const float* __restrict__ segsum,
                unsigned short* __restrict__ avgT) {
    int g = blockIdx.x * 256 + threadIdx.x;
    int d = g & (DD - 1);
    int s = (g >> 10) & (NSEG - 1);
    int b = g >> 15;
    float run = 0.f;
    const float* ss = segsum + ((size_t)b << 15) + d;
    for (int s2 = 0; s2 < s; ++s2) run += ss[s2 << 10];
    const float* p = x + (size_t)(b * LL + s * SEGLEN) * DD + d;
    unsigned short* rowt = avgT +
        ((size_t)(b * HH + (d >> 6)) * DH + (d & 63)) * TROW;
    unsigned short* qt = rowt + 32 + s * SEGLEN;
    if (s == 0) {   // zero the 32-token prefix (window padding)
        u16x8 z = {};
        #pragma unroll
        for (int j = 0; j < 4; ++j) *(u16x8*)&rowt[j * 8] = z;
    }
    int t0 = s * SEGLEN;
    #pragma unroll
    for (int j = 0; j < 8; ++j) {
        u16x8 v;
        #pragma unroll
        for (int e = 0; e < 8; ++e) {
            int i = j * 8 + e;
            run += p[(size_t)i * DD];
            v[e] = f2bf(run / (float)(t0 + i + 1));
        }
        *(u16x8*)&qt[j * 8] = v;
    }
}

// ------- Fused: pc = ci@W_pe+b_pe -> gated energy -> softmax -> local conv --
__global__ __launch_bounds__(256, 4)
void conv_kernel(const unsigned short* __restrict__ avgT,
                 const unsigned short* __restrict__ wpeT,
                 const float* __restrict__ b_pe, const float* __restrict__ stt,
                 unsigned short* __restrict__ conv) {
    __shared__ __align__(16) unsigned short pcs[64 * PCSS];     //  8192 B
    __shared__ __align__(16) unsigned short winT[64 * TSTR2];   // 14336 B
    __shared__ __align__(16) unsigned short wub[64 * WBSTR2];   // 13312 B

    int tid = threadIdx.x;
    int tile = blockIdx.x & 31;
    int bh = blockIdx.x >> 5;
    int b = bh >> 4, h = bh & 15;
    int t0 = tile * TLEN;
    int wv = tid >> 6, ln = tid & 63;
    int g = ln >> 4, li = ln & 15;

    // ---- phase 0: async staging (all global_load_lds width 16) ----
    {
        const unsigned short* gT = avgT + (size_t)(b * HH + h) * DH * TROW;
        #pragma unroll
        for (int q = 0; q < 3; ++q) {
            int i = tid + q * 256;
            int d = i / 14, c = i - d * 14;
            gload_lds16(gT + (size_t)d * TROW + t0 + c * 8, winT + (i & ~63) * 8);
        }
        if (tid < 128) {
            int i = 768 + tid;
            int d = i / 14, c = i - d * 14;
            gload_lds16(gT + (size_t)d * TROW + t0 + c * 8, winT + (i & ~63) * 8);
        }
        #pragma unroll
        for (int q = 0; q < 2; ++q) {
            int i = tid + q * 256;
            gload_lds16(wpeT + i * 8, wub + (i & ~63) * 8);
        }
        if (tid < 64) {
            int i = 512 + tid;
            gload_lds16(wpeT + i * 8, wub + (i & ~63) * 8);
        }
    }
    __syncthreads();

    // ---- phase 1: pc = ci @ W_pe via MFMA (A gathered from winT cols) ----
    f32x4 pacc[4];
    {
        int q32 = 32 + wv * 16 + li;   // window col of this token
        bf16x8 a0, a1;
        #pragma unroll
        for (int e = 0; e < 8; ++e) {
            a0[e] = (short)winT[(g * 8 + e) * TSTR2 + q32];
            a1[e] = (short)winT[(32 + g * 8 + e) * TSTR2 + q32];
        }
        #pragma unroll
        for (int n = 0; n < 4; ++n) {
            int c = n * 16 + li;
            bf16x8 b0 = *(const bf16x8*)&wub[c * WPESTR2 + g * 8];
            bf16x8 b1 = *(const bf16x8*)&wub[c * WPESTR2 + 32 + g * 8];
            f32x4 z = {0.f, 0.f, 0.f, 0.f};
            z = __builtin_amdgcn_mfma_f32_16x16x32_bf16(a0, b0, z, 0, 0, 0);
            z = __builtin_amdgcn_mfma_f32_16x16x32_bf16(a1, b1, z, 0, 0, 0);
            pacc[n] = z;
        }
    }
    __syncthreads();   // wpeT reads done; wub becomes wband below

    {   // pcs writes + zero wband (overlay wpeT)
        #pragma unroll
        for (int n = 0; n < 4; ++n) {
            int c = n * 16 + li;
            float bp = (c < 2 * KK) ? b_pe[c] : 0.f;
            #pragma unroll
            for (int r = 0; r < 4; ++r)
                pcs[(wv * 16 + g * 4 + r) * PCSS + c] = f2bf(pacc[n][r] + bp);
        }
        for (int i = tid; i < 64 * WBSTR2 / 8; i += 256) {
            u16x8 z = {};
            *(u16x8*)&wub[i * 8] = z;
        }
    }
    __syncthreads();

    // ---- phase 3: softmax (no max-reduce; energies bounded) -> wband ----
    {
        int half = ln >> 5, k = ln & 31;
        int kc = (k < KK) ? k : 0;
        float sttk = stt[h * KK + kc];
        for (int it = 0; it < 8; ++it) {
            int tok = wv * 16 + it * 2 + half;
            float dyn  = bf2f(pcs[tok * PCSS + kc]);
            float gate = bf2f(pcs[tok * PCSS + KK + kc]);
            float e = 0.f;
            if (k < KK) e = __expf(sttk + dyn / (1.f + __expf(-gate)));
            float sum = e;
            #pragma unroll
            for (int off = 16; off; off >>= 1) sum += __shfl_xor(sum, off, 64);
            float wvl = e / sum;
            if (k < KK && t0 + tok + k >= KK - 1)
                wub[tok * WBSTR2 + tok + k + 2] = f2bf(wvl);
        }
    }
    __syncthreads();

    // ---- phase 4: conv = wband @ winT^T via MFMA (K = 96) ----
    {
        int row = wv * 16 + li;
        bf16x8 wa0 = *(const bf16x8*)&wub[row * WBSTR2 + g * 8];
        bf16x8 wa1 = *(const bf16x8*)&wub[row * WBSTR2 + 32 + g * 8];
        bf16x8 wa2 = *(const bf16x8*)&wub[row * WBSTR2 + 64 + g * 8];
        f32x4 cacc[4];
        #pragma unroll
        for (int n = 0; n < 4; ++n) {
            int c = n * 16 + li;
            bf16x8 b0 = *(const bf16x8*)&winT[c * TSTR2 + g * 8];
            bf16x8 b1 = *(const bf16x8*)&winT[c * TSTR2 + 32 + g * 8];
            bf16x8 b2 = *(const bf16x8*)&winT[c * TSTR2 + 64 + g * 8];
            f32x4 z = {0.f, 0.f, 0.f, 0.f};
            z = __builtin_amdgcn_mfma_f32_16x16x32_bf16(wa0, b0, z, 0, 0, 0);
            z = __builtin_amdgcn_mfma_f32_16x16x32_bf16(wa1, b1, z, 0, 0, 0);
            z = __builtin_amdgcn_mfma_f32_16x16x32_bf16(wa2, b2, z, 0, 0, 0);
            cacc[n] = z;
        }
        #pragma unroll
        for (int n = 0; n < 4; ++n)
            #pragma unroll
            for (int r = 0; r < 4; ++r)
                pcs[(wv * 16 + g * 4 + r) * PCSS + n * 16 + li] =
                    f2bf(cacc[n][r]);
    }
    __syncthreads();

    // ---- phase 5: coalesced store ----
    {
        int tok = tid >> 2, j0 = (tid & 3) * 16;
        u16x8 v0 = *(const u16x8*)&pcs[tok * PCSS + j0];
        u16x8 v1 = *(const u16x8*)&pcs[tok * PCSS + j0 + 8];
        unsigned short* o = conv + (size_t)(b * LL + t0 + tok) * DD + h * DH + j0;
        *(u16x8*)&o[0] = v0;
        *(u16x8*)&o[8] = v1;
    }
}

// ---- W_fc f32 -> bf16 cast (2MB) + wpeT prep (block 1024) -----------------
__global__ __launch_bounds__(256)
void cvt_kernel(const float* __restrict__ in, unsigned short* __restrict__ out,
                const float* __restrict__ W_pe, unsigned short* __restrict__ wpeT) {
    if (blockIdx.x == 1024) {
        for (int i = threadIdx.x; i < 64 * WPESTR2; i += 256) {
            int c = i / WPESTR2, d = i - c * WPESTR2;
            float v = (c < 2 * KK && d < 64) ? W_pe[d * (2 * KK) + c] : 0.f;
            wpeT[i] = f2bf(v);
        }
        return;
    }
    int i = (blockIdx.x * 256 + threadIdx.x) * 4;
    float4 v = *(const float4*)&in[i];
    ushort4 o;
    o.x = f2bf(v.x); o.y = f2bf(v.y); o.z = f2bf(v.z); o.w = f2bf(v.w);
    *(ushort4*)&out[i] = o;
}

// ---- v = conv @ W_fc^T + x : 256x256 tile, FOUR waves (2x2), wave tile
//      128x128 -> halves per-CU LDS-read traffic (the measured 28%-MfmaUtil
//      bandwidth floor). BK=64, XOR swizzle, dbuf, counted vmcnt(16). -------
#define WAITV0()  do { asm volatile("s_waitcnt vmcnt(0)" ::: "memory"); \
                       __builtin_amdgcn_sched_barrier(0); } while (0)
#define WAITV16() do { asm volatile("s_waitcnt vmcnt(16)" ::: "memory"); \
                       __builtin_amdgcn_sched_barrier(0); } while (0)
#define BAR()     do { __builtin_amdgcn_sched_barrier(0); \
                       __builtin_amdgcn_s_barrier(); \
                       __builtin_amdgcn_sched_barrier(0); } while (0)

__global__ __launch_bounds__(256, 1)
void gemm_mfma_kernel(const unsigned short* __restrict__ A,
                      const unsigned short* __restrict__ Bt,
                      const float* __restrict__ X,
                      unsigned short* __restrict__ Vb)
{
    __shared__ __align__(16) unsigned short As0[256 * 64];   // 32 KB each
    __shared__ __align__(16) unsigned short Bs0[256 * 64];
    __shared__ __align__(16) unsigned short As1[256 * 64];
    __shared__ __align__(16) unsigned short Bs1[256 * 64];
    int tid = threadIdx.x;
    int wv = tid >> 6, ln = tid & 63;
    int bid = blockIdx.x;
    int nbid = (bid & 7) * 32 + (bid >> 3);   // XCD-contiguous (256%8==0)
    int bm0 = (nbid >> 2) * 256;              // 64 m-tiles
    int bn0 = (nbid & 3) * 256;               // 4 n-tiles
    int wr = wv >> 1, wc = wv & 1;            // 2x2 wave grid, 128x128/wave

    // staging: thread tid stages chunks {i*256+tid}, i=0..7, per panel.
    // row = i*32 + (tid>>3); chunk = tid&7; swizzled source chunk is
    // invariant in i: sc = (tid&7) ^ ((tid>>3)&7).
    int srow = tid >> 3;
    int sc = (tid & 7) ^ (srow & 7);
    const unsigned short* ga0 = A  + (size_t)(bm0 + srow) * 1024 + sc * 8;
    const unsigned short* gb0 = Bt + (size_t)(bn0 + srow) * 1024 + sc * 8;
    int ldo0 = tid * 8;

    f32x4 acc[8][8] = {};
    int la = wr * 128 + (ln & 15);
    int lb = wc * 128 + (ln & 15);
    int kg = ln >> 4;                          // 0..3
    int rxor = (ln & 7) * 8;                   // swizzle term (row&7 == ln&7)

#define STAGE(SA, SB, kt)                                           \
    { _Pragma("unroll")                                             \
      for (int i = 0; i < 8; ++i) {                                 \
          gload_lds16(ga0 + i * 32768 + (kt), SA + ldo0 + i * 2048);\
          gload_lds16(gb0 + i * 32768 + (kt), SB + ldo0 + i * 2048);\
      } }

#define MFMA_TILE(RA, RB)                                                     \
    { _Pragma("unroll")                                                       \
      for (int ks = 0; ks < 2; ++ks) {                                        \
          int cko = (((kg + ks * 4) * 8) ^ rxor);                             \
          bf16x8 bfr[8];                                                      \
          _Pragma("unroll")                                                   \
          for (int n = 0; n < 8; ++n)                                         \
              bfr[n] = *(const bf16x8*)&RB[(lb + n * 16) * 64 + cko];         \
          _Pragma("unroll")                                                   \
          for (int m = 0; m < 8; ++m) {                                       \
              bf16x8 af = *(const bf16x8*)&RA[(la + m * 16) * 64 + cko];      \
              __builtin_amdgcn_s_setprio(1);                                  \
              _Pragma("unroll")                                               \
              for (int n = 0; n < 8; ++n)                                     \
                  acc[m][n] = __builtin_amdgcn_mfma_f32_16x16x32_bf16(        \
                      af, bfr[n], acc[m][n], 0, 0, 0);                        \
              __builtin_amdgcn_s_setprio(0);                                  \
          }                                                                   \
      } }

    // prologue: tile 0 -> buf0 (16 DMAs/thread)
    STAGE(As0, Bs0, 0);
    unsigned short* Ac = As0; unsigned short* Bc = Bs0;
    unsigned short* An = As1; unsigned short* Bn = Bs1;
    for (int t = 0; t < 16; ++t) {
        bool last = (t == 15);
        if (!last) STAGE(An, Bn, (t + 1) * 64);
        if (last) { WAITV0(); } else { WAITV16(); }
        BAR();
        MFMA_TILE(Ac, Bc);
        BAR();
        unsigned short* tA = Ac; Ac = An; An = tA;
        unsigned short* tB = Bc; Bc = Bn; Bn = tB;
    }
#undef STAGE
#undef MFMA_TILE

    // epilogue: v = acc + X, store bf16
    int rb0 = bm0 + wr * 128 + (ln >> 4) * 4;
    int cb0 = bn0 + wc * 128 + (ln & 15);
    #pragma unroll
    for (int m = 0; m < 8; ++m) {
        #pragma unroll
        for (int r = 0; r < 4; ++r) {
            int row = rb0 + m * 16 + r;
            size_t off = (size_t)row * 1024 + cb0;
            #pragma unroll
            for (int n = 0; n < 8; ++n)
                Vb[off + n * 16] = f2bf(acc[m][n][r] + X[off + n * 16]);
        }
    }
}

// ---------------- LayerNorm from bf16 V (row reduce + apply) ---------------
__global__ __launch_bounds__(256)
void ln_kernel(const unsigned short* __restrict__ Vb,
               const float* __restrict__ gamma,
               const float* __restrict__ beta,
               float* __restrict__ out) {
    __shared__ float red[8];
    int row = blockIdx.x;
    int tid = threadIdx.x;
    ushort4 vu = *(const ushort4*)&Vb[(size_t)row * 1024 + tid * 4];
    float v0 = bf2f(vu.x), v1 = bf2f(vu.y), v2 = bf2f(vu.z), v3 = bf2f(vu.w);
    float s = v0 + v1 + v2 + v3;
    float s2 = v0 * v0 + v1 * v1 + v2 * v2 + v3 * v3;
    #pragma unroll
    for (int off = 32; off; off >>= 1) {
        s  += __shfl_xor(s, off, 64);
        s2 += __shfl_xor(s2, off, 64);
    }
    if ((tid & 63) == 0) { red[(tid >> 6) * 2] = s; red[(tid >> 6) * 2 + 1] = s2; }
    __syncthreads();
    s  = red[0] + red[2] + red[4] + red[6];
    s2 = red[1] + red[3] + red[5] + red[7];
    float mu = s * (1.f / 1024.f);
    float var = s2 * (1.f / 1024.f) - mu * mu;
    float rs = rsqrtf(var + 1e-6f);
    float4 g  = *(const float4*)&gamma[tid * 4];
    float4 be = *(const float4*)&beta[tid * 4];
    float4 o = make_float4((v0 - mu) * rs * g.x + be.x,
                           (v1 - mu) * rs * g.y + be.y,
                           (v2 - mu) * rs * g.z + be.z,
                           (v3 - mu) * rs * g.w + be.w);
    *(float4*)&out[(size_t)row * 1024 + tid * 4] = o;
}

extern "C" void kernel_launch(void* const* d_in, const int* in_sizes, int n_in,
                              void* d_out, int out_size, void* d_ws, size_t ws_size,
                              hipStream_t stream) {
    const float* x     = (const float*)d_in[0];
    const float* W_pe  = (const float*)d_in[1];
    const float* b_pe  = (const float*)d_in[2];
    const float* stt   = (const float*)d_in[3];
    const float* W_fc  = (const float*)d_in[4];
    const float* gamma = (const float*)d_in[5];
    const float* beta  = (const float*)d_in[6];
    float* out = (float*)d_out;

    char* ws = (char*)d_ws;
    unsigned short* Vb    = (unsigned short*)ws;                               // 32 MB
    unsigned short* avgT  = (unsigned short*)(ws + (size_t)32 * 1024 * 1024);  // 32.5 MB
    unsigned short* convb = (unsigned short*)(ws + (size_t)68 * 1024 * 1024);  // 32 MB
    unsigned short* wfcb  = (unsigned short*)(ws + (size_t)100 * 1024 * 1024); //  2 MB
    unsigned short* wpeT  = (unsigned short*)(ws + (size_t)102 * 1024 * 1024); //  9 KB
    float*          segs  = (float*)(ws + (size_t)103 * 1024 * 1024);          //  1 MB

    seg_sum_kernel<<<1024, 256, 0, stream>>>(x, segs);
    avg_kernel<<<1024, 256, 0, stream>>>(x, segs, avgT);
    cvt_kernel<<<1025, 256, 0, stream>>>(W_fc, wfcb, W_pe, wpeT);
    conv_kernel<<<4096, 256, 0, stream>>>(avgT, wpeT, b_pe, stt, convb);
    gemm_mfma_kernel<<<256, 256, 0, stream>>>(convb, wfcb, x, Vb);
    ln_kernel<<<16384, 256, 0, stream>>>(Vb, gamma, beta, out);
}

// Round 18
// 151.718 us; speedup vs baseline: 1.0282x; 1.0282x over previous
//
#include <hip/hip_runtime.h>
#include <math.h>

// Problem constants (B,L,D,H,K) = (8, 2048, 1024, 16, 31)
#define BB 8
#define LL 2048
#define DD 1024
#define HH 16
#define DH 64          // D/H
#define KK 31
#define NSEG 32
#define SEGLEN 64      // LL/NSEG

#define TLEN 64        // tokens per conv block
#define TROW 2080      // avgT row stride (u16): 32-zero prefix + 2048 tokens
#define TSTR2 112      // winT row stride (u16): 14 chunks of 16B
#define WBSTR2 104     // wband row stride (u16): 208B
#define WPESTR2 72     // wpeT row stride (u16): 144B
#define PCSS 64        // pcs row stride (u16): row-internal accesses only

typedef __attribute__((ext_vector_type(8))) short bf16x8;
typedef __attribute__((ext_vector_type(4))) float f32x4;
typedef __attribute__((ext_vector_type(8))) unsigned short u16x8;

__device__ __forceinline__ unsigned short f2bf(float f) {
    unsigned u = __float_as_uint(f);
    unsigned r = (u + 0x7fffu + ((u >> 16) & 1u)) >> 16;   // RNE
    return (unsigned short)r;
}
__device__ __forceinline__ float bf2f(unsigned short s) {
    return __uint_as_float(((unsigned)s) << 16);
}

__device__ __forceinline__ void gload_lds16(const void* g, void* l) {
    __builtin_amdgcn_global_load_lds(
        (const __attribute__((address_space(1))) void*)g,
        (__attribute__((address_space(3))) void*)l, 16, 0, 0);
}

// ---------------- Pass 1a: per-segment sums (for parallel cumsum) ----------
__global__ __launch_bounds__(256)
void seg_sum_kernel(const float* __restrict__ x, float* __restrict__ segsum) {
    int g = blockIdx.x * 256 + threadIdx.x;   // B*NSEG*D threads
    int d = g & (DD - 1);
    int s = (g >> 10) & (NSEG - 1);
    int b = g >> 15;
    const float* p = x + (size_t)(b * LL + s * SEGLEN) * DD + d;
    float acc = 0.f;
    #pragma unroll 8
    for (int i = 0; i < SEGLEN; ++i) acc += p[(size_t)i * DD];
    segsum[g] = acc;   // layout [b][s][d] == flat g
}

// ---- Pass 1b: running mean -> avgT [b,h,d][32zero|2048]; also xb = bf16(x) -
__global__ __launch_bounds__(256)
void avg_kernel(const float* __restrict__ x, const float* __restrict__ segsum,
                unsigned short* __restrict__ avgT,
                unsigned short* __restrict__ xb) {
    int g = blockIdx.x * 256 + threadIdx.x;
    int d = g & (DD - 1);
    int s = (g >> 10) & (NSEG - 1);
    int b = g >> 15;
    float run = 0.f;
    const float* ss = segsum + ((size_t)b << 15) + d;
    for (int s2 = 0; s2 < s; ++s2) run += ss[s2 << 10];
    const float* p = x + (size_t)(b * LL + s * SEGLEN) * DD + d;
    unsigned short* qx = xb + (size_t)(b * LL + s * SEGLEN) * DD + d;
    unsigned short* rowt = avgT +
        ((size_t)(b * HH + (d >> 6)) * DH + (d & 63)) * TROW;
    unsigned short* qt = rowt + 32 + s * SEGLEN;
    if (s == 0) {   // zero the 32-token prefix (window padding)
        u16x8 z = {};
        #pragma unroll
        for (int j = 0; j < 4; ++j) *(u16x8*)&rowt[j * 8] = z;
    }
    int t0 = s * SEGLEN;
    #pragma unroll
    for (int j = 0; j < 8; ++j) {
        u16x8 v;
        #pragma unroll
        for (int e = 0; e < 8; ++e) {
            int i = j * 8 + e;
            float xv = p[(size_t)i * DD];
            run += xv;
            qx[(size_t)i * DD] = f2bf(xv);
            v[e] = f2bf(run / (float)(t0 + i + 1));
        }
        *(u16x8*)&qt[j * 8] = v;
    }
}

// ------- Fused: pc = ci@W_pe+b_pe -> gated energy -> softmax -> local conv --
__global__ __launch_bounds__(256, 4)
void conv_kernel(const unsigned short* __restrict__ avgT,
                 const unsigned short* __restrict__ wpeT,
                 const float* __restrict__ b_pe, const float* __restrict__ stt,
                 unsigned short* __restrict__ conv) {
    __shared__ __align__(16) unsigned short pcs[64 * PCSS];     //  8192 B
    __shared__ __align__(16) unsigned short winT[64 * TSTR2];   // 14336 B
    __shared__ __align__(16) unsigned short wub[64 * WBSTR2];   // 13312 B

    int tid = threadIdx.x;
    int tile = blockIdx.x & 31;
    int bh = blockIdx.x >> 5;
    int b = bh >> 4, h = bh & 15;
    int t0 = tile * TLEN;
    int wv = tid >> 6, ln = tid & 63;
    int g = ln >> 4, li = ln & 15;

    // ---- phase 0: async staging (all global_load_lds width 16) ----
    {
        const unsigned short* gT = avgT + (size_t)(b * HH + h) * DH * TROW;
        #pragma unroll
        for (int q = 0; q < 3; ++q) {
            int i = tid + q * 256;
            int d = i / 14, c = i - d * 14;
            gload_lds16(gT + (size_t)d * TROW + t0 + c * 8, winT + (i & ~63) * 8);
        }
        if (tid < 128) {
            int i = 768 + tid;
            int d = i / 14, c = i - d * 14;
            gload_lds16(gT + (size_t)d * TROW + t0 + c * 8, winT + (i & ~63) * 8);
        }
        #pragma unroll
        for (int q = 0; q < 2; ++q) {
            int i = tid + q * 256;
            gload_lds16(wpeT + i * 8, wub + (i & ~63) * 8);
        }
        if (tid < 64) {
            int i = 512 + tid;
            gload_lds16(wpeT + i * 8, wub + (i & ~63) * 8);
        }
    }
    __syncthreads();

    // ---- phase 1: pc = ci @ W_pe via MFMA (A gathered from winT cols) ----
    f32x4 pacc[4];
    {
        int q32 = 32 + wv * 16 + li;   // window col of this token
        bf16x8 a0, a1;
        #pragma unroll
        for (int e = 0; e < 8; ++e) {
            a0[e] = (short)winT[(g * 8 + e) * TSTR2 + q32];
            a1[e] = (short)winT[(32 + g * 8 + e) * TSTR2 + q32];
        }
        #pragma unroll
        for (int n = 0; n < 4; ++n) {
            int c = n * 16 + li;
            bf16x8 b0 = *(const bf16x8*)&wub[c * WPESTR2 + g * 8];
            bf16x8 b1 = *(const bf16x8*)&wub[c * WPESTR2 + 32 + g * 8];
            f32x4 z = {0.f, 0.f, 0.f, 0.f};
            z = __builtin_amdgcn_mfma_f32_16x16x32_bf16(a0, b0, z, 0, 0, 0);
            z = __builtin_amdgcn_mfma_f32_16x16x32_bf16(a1, b1, z, 0, 0, 0);
            pacc[n] = z;
        }
    }
    __syncthreads();   // wpeT reads done; wub becomes wband below

    {   // pcs writes + zero wband (overlay wpeT)
        #pragma unroll
        for (int n = 0; n < 4; ++n) {
            int c = n * 16 + li;
            float bp = (c < 2 * KK) ? b_pe[c] : 0.f;
            #pragma unroll
            for (int r = 0; r < 4; ++r)
                pcs[(wv * 16 + g * 4 + r) * PCSS + c] = f2bf(pacc[n][r] + bp);
        }
        for (int i = tid; i < 64 * WBSTR2 / 8; i += 256) {
            u16x8 z = {};
            *(u16x8*)&wub[i * 8] = z;
        }
    }
    __syncthreads();

    // ---- phase 3: softmax (no max-reduce; energies bounded) -> wband ----
    {
        int half = ln >> 5, k = ln & 31;
        int kc = (k < KK) ? k : 0;
        float sttk = stt[h * KK + kc];
        for (int it = 0; it < 8; ++it) {
            int tok = wv * 16 + it * 2 + half;
            float dyn  = bf2f(pcs[tok * PCSS + kc]);
            float gate = bf2f(pcs[tok * PCSS + KK + kc]);
            float e = 0.f;
            if (k < KK) e = __expf(sttk + dyn / (1.f + __expf(-gate)));
            float sum = e;
            #pragma unroll
            for (int off = 16; off; off >>= 1) sum += __shfl_xor(sum, off, 64);
            float wvl = e / sum;
            if (k < KK && t0 + tok + k >= KK - 1)
                wub[tok * WBSTR2 + tok + k + 2] = f2bf(wvl);
        }
    }
    __syncthreads();

    // ---- phase 4: conv = wband @ winT^T via MFMA (K = 96) ----
    {
        int row = wv * 16 + li;
        bf16x8 wa0 = *(const bf16x8*)&wub[row * WBSTR2 + g * 8];
        bf16x8 wa1 = *(const bf16x8*)&wub[row * WBSTR2 + 32 + g * 8];
        bf16x8 wa2 = *(const bf16x8*)&wub[row * WBSTR2 + 64 + g * 8];
        f32x4 cacc[4];
        #pragma unroll
        for (int n = 0; n < 4; ++n) {
            int c = n * 16 + li;
            bf16x8 b0 = *(const bf16x8*)&winT[c * TSTR2 + g * 8];
            bf16x8 b1 = *(const bf16x8*)&winT[c * TSTR2 + 32 + g * 8];
            bf16x8 b2 = *(const bf16x8*)&winT[c * TSTR2 + 64 + g * 8];
            f32x4 z = {0.f, 0.f, 0.f, 0.f};
            z = __builtin_amdgcn_mfma_f32_16x16x32_bf16(wa0, b0, z, 0, 0, 0);
            z = __builtin_amdgcn_mfma_f32_16x16x32_bf16(wa1, b1, z, 0, 0, 0);
            z = __builtin_amdgcn_mfma_f32_16x16x32_bf16(wa2, b2, z, 0, 0, 0);
            cacc[n] = z;
        }
        #pragma unroll
        for (int n = 0; n < 4; ++n)
            #pragma unroll
            for (int r = 0; r < 4; ++r)
                pcs[(wv * 16 + g * 4 + r) * PCSS + n * 16 + li] =
                    f2bf(cacc[n][r]);
    }
    __syncthreads();

    // ---- phase 5: coalesced store ----
    {
        int tok = tid >> 2, j0 = (tid & 3) * 16;
        u16x8 v0 = *(const u16x8*)&pcs[tok * PCSS + j0];
        u16x8 v1 = *(const u16x8*)&pcs[tok * PCSS + j0 + 8];
        unsigned short* o = conv + (size_t)(b * LL + t0 + tok) * DD + h * DH + j0;
        *(u16x8*)&o[0] = v0;
        *(u16x8*)&o[8] = v1;
    }
}

// ---- W_fc f32 -> bf16 cast (2MB) + wpeT prep (block 1024) -----------------
__global__ __launch_bounds__(256)
void cvt_kernel(const float* __restrict__ in, unsigned short* __restrict__ out,
                const float* __restrict__ W_pe, unsigned short* __restrict__ wpeT) {
    if (blockIdx.x == 1024) {
        for (int i = threadIdx.x; i < 64 * WPESTR2; i += 256) {
            int c = i / WPESTR2, d = i - c * WPESTR2;
            float v = (c < 2 * KK && d < 64) ? W_pe[d * (2 * KK) + c] : 0.f;
            wpeT[i] = f2bf(v);
        }
        return;
    }
    int i = (blockIdx.x * 256 + threadIdx.x) * 4;
    float4 v = *(const float4*)&in[i];
    ushort4 o;
    o.x = f2bf(v.x); o.y = f2bf(v.y); o.z = f2bf(v.z); o.w = f2bf(v.w);
    *(ushort4*)&out[i] = o;
}

// ---- v = conv @ W_fc^T + x : 256x256 tile, 8 waves, BK=64, XOR-swizzled
//      LDS, double-buffered, 4 phases/K-tile with COUNTED vmcnt matched to
//      first-use (r16 schedule, best measured). Residual read as bf16 xb. ---
#define WAITV0() do { asm volatile("s_waitcnt vmcnt(0)" ::: "memory"); \
                      __builtin_amdgcn_sched_barrier(0); } while (0)
#define WAITV2() do { asm volatile("s_waitcnt vmcnt(2)" ::: "memory"); \
                      __builtin_amdgcn_sched_barrier(0); } while (0)
#define WAITV4() do { asm volatile("s_waitcnt vmcnt(4)" ::: "memory"); \
                      __builtin_amdgcn_sched_barrier(0); } while (0)
#define LGK0()   do { asm volatile("s_waitcnt lgkmcnt(0)" ::: "memory"); \
                      __builtin_amdgcn_sched_barrier(0); } while (0)
#define BAR()    do { __builtin_amdgcn_sched_barrier(0); \
                      __builtin_amdgcn_s_barrier(); \
                      __builtin_amdgcn_sched_barrier(0); } while (0)

__global__ __launch_bounds__(512, 2)
void gemm_mfma_kernel(const unsigned short* __restrict__ A,
                      const unsigned short* __restrict__ Bt,
                      const unsigned short* __restrict__ Xb,
                      unsigned short* __restrict__ Vb)
{
    __shared__ __align__(16) unsigned short As0[256 * 64];   // 32 KB each
    __shared__ __align__(16) unsigned short Bs0[256 * 64];
    __shared__ __align__(16) unsigned short As1[256 * 64];
    __shared__ __align__(16) unsigned short Bs1[256 * 64];
    int tid = threadIdx.x;
    int wv = tid >> 6, ln = tid & 63;
    int bid = blockIdx.x;
    int nbid = (bid & 7) * 32 + (bid >> 3);   // XCD-contiguous (256%8==0)
    int bm0 = (nbid >> 2) * 256;              // 64 m-tiles
    int bn0 = (nbid & 3) * 256;               // 4 n-tiles
    int wr = wv >> 2, wc = wv & 3;            // 2x4 wave grid

    // load i covers quarter i (rows i*64..i*64+63) of the 256-row panel
    const unsigned short* ga[4];
    const unsigned short* gb[4];
    int ldo[4];
    #pragma unroll
    for (int i = 0; i < 4; ++i) {
        int dci = i * 512 + wv * 64 + ln;     // dest chunk index (16B units)
        int row = dci >> 3, ch = dci & 7;
        int sc = ch ^ (row & 7);
        ga[i] = A  + (size_t)(bm0 + row) * 1024 + sc * 8;
        gb[i] = Bt + (size_t)(bn0 + row) * 1024 + sc * 8;
        ldo[i] = dci * 8;                      // u16 offset, linear dest
    }

    f32x4 acc[8][4] = {};
    int la = wr * 128 + (ln & 15);
    int lb = wc * 64 + (ln & 15);
    int kg = ln >> 4;                          // 0..3

#define READ_BFR(RB)                                                          \
    _Pragma("unroll")                                                         \
    for (int n = 0; n < 4; ++n)                                               \
      _Pragma("unroll")                                                       \
      for (int ks = 0; ks < 2; ++ks) {                                        \
        int row = lb + n * 16;                                                \
        bfr[n][ks] = *(const bf16x8*)&RB[row * 64 +                           \
                        (((kg + ks * 4) ^ (row & 7)) * 8)];                   \
      }

#define READ_AF(RA, MQ)                                                       \
    _Pragma("unroll")                                                         \
    for (int mm = 0; mm < 2; ++mm)                                            \
      _Pragma("unroll")                                                       \
      for (int ks = 0; ks < 2; ++ks) {                                        \
        int row = la + ((MQ) * 2 + mm) * 16;                                  \
        af[mm][ks] = *(const bf16x8*)&RA[row * 64 +                           \
                        (((kg + ks * 4) ^ (row & 7)) * 8)];                   \
      }

#define MFMAQ(MQ)                                                             \
    __builtin_amdgcn_s_setprio(1);                                            \
    _Pragma("unroll")                                                         \
    for (int mm = 0; mm < 2; ++mm)                                            \
      _Pragma("unroll")                                                       \
      for (int n = 0; n < 4; ++n)                                             \
        _Pragma("unroll")                                                     \
        for (int ks = 0; ks < 2; ++ks)                                        \
          acc[(MQ) * 2 + mm][n] = __builtin_amdgcn_mfma_f32_16x16x32_bf16(    \
              af[mm][ks], bfr[n][ks], acc[(MQ) * 2 + mm][n], 0, 0, 0);        \
    __builtin_amdgcn_s_setprio(0);

    // prologue: stage tile 0 -> buf0 in first-use order
    gload_lds16(gb[0], Bs0 + ldo[0]);
    gload_lds16(gb[1], Bs0 + ldo[1]);
    gload_lds16(gb[2], Bs0 + ldo[2]);
    gload_lds16(gb[3], Bs0 + ldo[3]);
    gload_lds16(ga[0], As0 + ldo[0]);
    gload_lds16(ga[2], As0 + ldo[2]);
    gload_lds16(ga[1], As0 + ldo[1]);
    gload_lds16(ga[3], As0 + ldo[3]);
    WAITV2(); BAR();   // B + even-A published; odd-A (2) still in flight

    unsigned short* Ac = As0; unsigned short* Bc = Bs0;
    unsigned short* An = As1; unsigned short* Bn = Bs1;
    for (int t = 0; t < 16; ++t) {
        int ktn = (t + 1) * 64;
        bool last = (t == 15);
        bf16x8 bfr[4][2], af[2][2];
        // ---- phase 0: bfr + af-q0 (even A-quarter); stage gb'[0..1] ----
        READ_BFR(Bc); READ_AF(Ac, 0);
        if (!last) { gload_lds16(gb[0] + ktn, Bn + ldo[0]);
                     gload_lds16(gb[1] + ktn, Bn + ldo[1]); }
        BAR(); LGK0();
        MFMAQ(0);
        BAR();
        // ---- phase 1: af-q1 (even A-quarter); stage gb'[2..3];
        //      then ensure this tile's odd A-quarters landed ----
        READ_AF(Ac, 1);
        if (!last) { gload_lds16(gb[2] + ktn, Bn + ldo[2]);
                     gload_lds16(gb[3] + ktn, Bn + ldo[3]); }
        BAR(); LGK0();
        MFMAQ(1);
        if (last) { WAITV0(); } else { WAITV4(); }
        BAR();
        // ---- phase 2: af-q2 (odd A-quarter); stage ga'[0],ga'[2] ----
        READ_AF(Ac, 2);
        if (!last) { gload_lds16(ga[0] + ktn, An + ldo[0]);
                     gload_lds16(ga[2] + ktn, An + ldo[2]); }
        BAR(); LGK0();
        MFMAQ(2);
        BAR();
        // ---- phase 3: af-q3 (odd A-quarter); stage ga'[1],ga'[3];
        //      then ensure next tile's B + even-A landed ----
        READ_AF(Ac, 3);
        if (!last) { gload_lds16(ga[1] + ktn, An + ldo[1]);
                     gload_lds16(ga[3] + ktn, An + ldo[3]); }
        BAR(); LGK0();
        MFMAQ(3);
        if (!last) WAITV2();
        BAR();
        // swap buffers
        unsigned short* tA = Ac; Ac = An; An = tA;
        unsigned short* tB = Bc; Bc = Bn; Bn = tB;
    }
#undef READ_BFR
#undef READ_AF
#undef MFMAQ

    // epilogue: v = acc + xb (bf16 residual), store bf16
    int rb0 = bm0 + wr * 128 + (ln >> 4) * 4;
    int cb0 = bn0 + wc * 64 + (ln & 15);
    #pragma unroll
    for (int m = 0; m < 8; ++m) {
        #pragma unroll
        for (int r = 0; r < 4; ++r) {
            int row = rb0 + m * 16 + r;
            size_t off = (size_t)row * 1024 + cb0;
            #pragma unroll
            for (int n = 0; n < 4; ++n)
                Vb[off + n * 16] =
                    f2bf(acc[m][n][r] + bf2f(Xb[off + n * 16]));
        }
    }
}

// ---------------- LayerNorm from bf16 V (row reduce + apply) ---------------
__global__ __launch_bounds__(256)
void ln_kernel(const unsigned short* __restrict__ Vb,
               const float* __restrict__ gamma,
               const float* __restrict__ beta,
               float* __restrict__ out) {
    __shared__ float red[8];
    int row = blockIdx.x;
    int tid = threadIdx.x;
    ushort4 vu = *(const ushort4*)&Vb[(size_t)row * 1024 + tid * 4];
    float v0 = bf2f(vu.x), v1 = bf2f(vu.y), v2 = bf2f(vu.z), v3 = bf2f(vu.w);
    float s = v0 + v1 + v2 + v3;
    float s2 = v0 * v0 + v1 * v1 + v2 * v2 + v3 * v3;
    #pragma unroll
    for (int off = 32; off; off >>= 1) {
        s  += __shfl_xor(s, off, 64);
        s2 += __shfl_xor(s2, off, 64);
    }
    if ((tid & 63) == 0) { red[(tid >> 6) * 2] = s; red[(tid >> 6) * 2 + 1] = s2; }
    __syncthreads();
    s  = red[0] + red[2] + red[4] + red[6];
    s2 = red[1] + red[3] + red[5] + red[7];
    float mu = s * (1.f / 1024.f);
    float var = s2 * (1.f / 1024.f) - mu * mu;
    float rs = rsqrtf(var + 1e-6f);
    float4 g  = *(const float4*)&gamma[tid * 4];
    float4 be = *(const float4*)&beta[tid * 4];
    float4 o = make_float4((v0 - mu) * rs * g.x + be.x,
                           (v1 - mu) * rs * g.y + be.y,
                           (v2 - mu) * rs * g.z + be.z,
                           (v3 - mu) * rs * g.w + be.w);
    *(float4*)&out[(size_t)row * 1024 + tid * 4] = o;
}

extern "C" void kernel_launch(void* const* d_in, const int* in_sizes, int n_in,
                              void* d_out, int out_size, void* d_ws, size_t ws_size,
                              hipStream_t stream) {
    const float* x     = (const float*)d_in[0];
    const float* W_pe  = (const float*)d_in[1];
    const float* b_pe  = (const float*)d_in[2];
    const float* stt   = (const float*)d_in[3];
    const float* W_fc  = (const float*)d_in[4];
    const float* gamma = (const float*)d_in[5];
    const float* beta  = (const float*)d_in[6];
    float* out = (float*)d_out;

    char* ws = (char*)d_ws;
    unsigned short* Vb    = (unsigned short*)ws;                               // 32 MB
    unsigned short* avgT  = (unsigned short*)(ws + (size_t)32 * 1024 * 1024);  // 32.5 MB
    unsigned short* convb = (unsigned short*)(ws + (size_t)68 * 1024 * 1024);  // 32 MB
    unsigned short* wfcb  = (unsigned short*)(ws + (size_t)100 * 1024 * 1024); //  2 MB
    unsigned short* wpeT  = (unsigned short*)(ws + (size_t)102 * 1024 * 1024); //  9 KB
    float*          segs  = (float*)(ws + (size_t)103 * 1024 * 1024);          //  1 MB
    unsigned short* xb    = (unsigned short*)(ws + (size_t)104 * 1024 * 1024); // 32 MB

    seg_sum_kernel<<<1024, 256, 0, stream>>>(x, segs);
    avg_kernel<<<1024, 256, 0, stream>>>(x, segs, avgT, xb);
    cvt_kernel<<<1025, 256, 0, stream>>>(W_fc, wfcb, W_pe, wpeT);
    conv_kernel<<<4096, 256, 0, stream>>>(avgT, wpeT, b_pe, stt, convb);
    gemm_mfma_kernel<<<256, 512, 0, stream>>>(convb, wfcb, xb, Vb);
    ln_kernel<<<16384, 256, 0, stream>>>(Vb, gamma, beta, out);
}

// Round 19
// 147.298 us; speedup vs baseline: 1.0590x; 1.0300x over previous
//
#include <hip/hip_runtime.h>
#include <math.h>

// Problem constants (B,L,D,H,K) = (8, 2048, 1024, 16, 31)
#define BB 8
#define LL 2048
#define DD 1024
#define HH 16
#define DH 64          // D/H
#define KK 31
#define NSEG 32
#define SEGLEN 64      // LL/NSEG

#define TLEN 64        // tokens per conv block
#define TROW 2080      // avgT row stride (u16): 32-zero prefix + 2048 tokens
#define TSTR2 112      // winT row stride (u16): 14 chunks of 16B
#define WBSTR2 104     // wband row stride (u16): 208B
#define WPESTR2 72     // wpeT row stride (u16): 144B
#define PCSS 64        // pcs row stride (u16): row-internal accesses only

typedef __attribute__((ext_vector_type(8))) short bf16x8;
typedef __attribute__((ext_vector_type(4))) float f32x4;
typedef __attribute__((ext_vector_type(8))) unsigned short u16x8;

__device__ __forceinline__ unsigned short f2bf(float f) {
    unsigned u = __float_as_uint(f);
    unsigned r = (u + 0x7fffu + ((u >> 16) & 1u)) >> 16;   // RNE
    return (unsigned short)r;
}
__device__ __forceinline__ float bf2f(unsigned short s) {
    return __uint_as_float(((unsigned)s) << 16);
}

__device__ __forceinline__ void gload_lds16(const void* g, void* l) {
    __builtin_amdgcn_global_load_lds(
        (const __attribute__((address_space(1))) void*)g,
        (__attribute__((address_space(3))) void*)l, 16, 0, 0);
}

// ---- Pass 1a: per-segment sums; float4 over d (4 d per thread) ------------
__global__ __launch_bounds__(256)
void seg_sum_kernel(const float* __restrict__ x, float* __restrict__ segsum) {
    int g = blockIdx.x * 256 + threadIdx.x;   // B*NSEG*(D/4) threads
    int d4 = (g & 255) * 4;
    int s = (g >> 8) & (NSEG - 1);
    int b = g >> 13;
    const float* p = x + (size_t)(b * LL + s * SEGLEN) * DD + d4;
    float4 acc = make_float4(0.f, 0.f, 0.f, 0.f);
    #pragma unroll 8
    for (int i = 0; i < SEGLEN; ++i) {
        float4 v = *(const float4*)&p[(size_t)i * DD];
        acc.x += v.x; acc.y += v.y; acc.z += v.z; acc.w += v.w;
    }
    *(float4*)&segsum[((size_t)b << 15) + (s << 10) + d4] = acc;
}

// ---- Pass 1b: running mean -> avgT [b,h,d][32zero|2048]; float4 x reads ---
__global__ __launch_bounds__(256)
void avg_kernel(const float* __restrict__ x, const float* __restrict__ segsum,
                unsigned short* __restrict__ avgT) {
    int g = blockIdx.x * 256 + threadIdx.x;   // B*NSEG*(D/4) threads
    int d4 = (g & 255) * 4;
    int s = (g >> 8) & (NSEG - 1);
    int b = g >> 13;
    float4 run = make_float4(0.f, 0.f, 0.f, 0.f);
    const float* ss = segsum + ((size_t)b << 15) + d4;
    for (int s2 = 0; s2 < s; ++s2) {
        float4 v = *(const float4*)&ss[s2 << 10];
        run.x += v.x; run.y += v.y; run.z += v.z; run.w += v.w;
    }
    const float* p = x + (size_t)(b * LL + s * SEGLEN) * DD + d4;
    unsigned short* rowt = avgT +
        ((size_t)(b * HH + (d4 >> 6)) * DH + (d4 & 63)) * TROW;
    if (s == 0) {   // zero the 32-token prefix of the 4 rows
        u16x8 z = {};
        #pragma unroll
        for (int dd = 0; dd < 4; ++dd)
            #pragma unroll
            for (int j = 0; j < 4; ++j)
                *(u16x8*)&rowt[dd * TROW + j * 8] = z;
    }
    int t0 = s * SEGLEN;
    #pragma unroll
    for (int j = 0; j < 8; ++j) {
        u16x8 v0, v1, v2, v3;
        #pragma unroll
        for (int e = 0; e < 8; ++e) {
            int i = j * 8 + e;
            float4 xv = *(const float4*)&p[(size_t)i * DD];
            run.x += xv.x; run.y += xv.y; run.z += xv.z; run.w += xv.w;
            float inv = 1.f / (float)(t0 + i + 1);
            v0[e] = f2bf(run.x * inv);
            v1[e] = f2bf(run.y * inv);
            v2[e] = f2bf(run.z * inv);
            v3[e] = f2bf(run.w * inv);
        }
        unsigned short* qt = rowt + 32 + t0 + j * 8;
        *(u16x8*)&qt[0 * TROW] = v0;
        *(u16x8*)&qt[1 * TROW] = v1;
        *(u16x8*)&qt[2 * TROW] = v2;
        *(u16x8*)&qt[3 * TROW] = v3;
    }
}

// ------- Fused: pc = ci@W_pe+b_pe -> gated energy -> softmax -> local conv --
__global__ __launch_bounds__(256, 4)
void conv_kernel(const unsigned short* __restrict__ avgT,
                 const unsigned short* __restrict__ wpeT,
                 const float* __restrict__ b_pe, const float* __restrict__ stt,
                 unsigned short* __restrict__ conv) {
    __shared__ __align__(16) unsigned short pcs[64 * PCSS];     //  8192 B
    __shared__ __align__(16) unsigned short winT[64 * TSTR2];   // 14336 B
    __shared__ __align__(16) unsigned short wub[64 * WBSTR2];   // 13312 B

    int tid = threadIdx.x;
    int tile = blockIdx.x & 31;
    int bh = blockIdx.x >> 5;
    int b = bh >> 4, h = bh & 15;
    int t0 = tile * TLEN;
    int wv = tid >> 6, ln = tid & 63;
    int g = ln >> 4, li = ln & 15;

    // ---- phase 0: async staging (all global_load_lds width 16) ----
    {
        const unsigned short* gT = avgT + (size_t)(b * HH + h) * DH * TROW;
        #pragma unroll
        for (int q = 0; q < 3; ++q) {
            int i = tid + q * 256;
            int d = i / 14, c = i - d * 14;
            gload_lds16(gT + (size_t)d * TROW + t0 + c * 8, winT + (i & ~63) * 8);
        }
        if (tid < 128) {
            int i = 768 + tid;
            int d = i / 14, c = i - d * 14;
            gload_lds16(gT + (size_t)d * TROW + t0 + c * 8, winT + (i & ~63) * 8);
        }
        #pragma unroll
        for (int q = 0; q < 2; ++q) {
            int i = tid + q * 256;
            gload_lds16(wpeT + i * 8, wub + (i & ~63) * 8);
        }
        if (tid < 64) {
            int i = 512 + tid;
            gload_lds16(wpeT + i * 8, wub + (i & ~63) * 8);
        }
    }
    __syncthreads();

    // ---- phase 1: pc = ci @ W_pe via MFMA (A gathered from winT cols) ----
    f32x4 pacc[4];
    {
        int q32 = 32 + wv * 16 + li;   // window col of this token
        bf16x8 a0, a1;
        #pragma unroll
        for (int e = 0; e < 8; ++e) {
            a0[e] = (short)winT[(g * 8 + e) * TSTR2 + q32];
            a1[e] = (short)winT[(32 + g * 8 + e) * TSTR2 + q32];
        }
        #pragma unroll
        for (int n = 0; n < 4; ++n) {
            int c = n * 16 + li;
            bf16x8 b0 = *(const bf16x8*)&wub[c * WPESTR2 + g * 8];
            bf16x8 b1 = *(const bf16x8*)&wub[c * WPESTR2 + 32 + g * 8];
            f32x4 z = {0.f, 0.f, 0.f, 0.f};
            z = __builtin_amdgcn_mfma_f32_16x16x32_bf16(a0, b0, z, 0, 0, 0);
            z = __builtin_amdgcn_mfma_f32_16x16x32_bf16(a1, b1, z, 0, 0, 0);
            pacc[n] = z;
        }
    }
    __syncthreads();   // wpeT reads done; wub becomes wband below

    {   // pcs writes + zero wband (overlay wpeT)
        #pragma unroll
        for (int n = 0; n < 4; ++n) {
            int c = n * 16 + li;
            float bp = (c < 2 * KK) ? b_pe[c] : 0.f;
            #pragma unroll
            for (int r = 0; r < 4; ++r)
                pcs[(wv * 16 + g * 4 + r) * PCSS + c] = f2bf(pacc[n][r] + bp);
        }
        for (int i = tid; i < 64 * WBSTR2 / 8; i += 256) {
            u16x8 z = {};
            *(u16x8*)&wub[i * 8] = z;
        }
    }
    __syncthreads();

    // ---- phase 3: softmax (no max-reduce; energies bounded) -> wband ----
    {
        int half = ln >> 5, k = ln & 31;
        int kc = (k < KK) ? k : 0;
        float sttk = stt[h * KK + kc];
        for (int it = 0; it < 8; ++it) {
            int tok = wv * 16 + it * 2 + half;
            float dyn  = bf2f(pcs[tok * PCSS + kc]);
            float gate = bf2f(pcs[tok * PCSS + KK + kc]);
            float e = 0.f;
            if (k < KK) e = __expf(sttk + dyn / (1.f + __expf(-gate)));
            float sum = e;
            #pragma unroll
            for (int off = 16; off; off >>= 1) sum += __shfl_xor(sum, off, 64);
            float wvl = e / sum;
            if (k < KK && t0 + tok + k >= KK - 1)
                wub[tok * WBSTR2 + tok + k + 2] = f2bf(wvl);
        }
    }
    __syncthreads();

    // ---- phase 4: conv = wband @ winT^T via MFMA (K = 96) ----
    {
        int row = wv * 16 + li;
        bf16x8 wa0 = *(const bf16x8*)&wub[row * WBSTR2 + g * 8];
        bf16x8 wa1 = *(const bf16x8*)&wub[row * WBSTR2 + 32 + g * 8];
        bf16x8 wa2 = *(const bf16x8*)&wub[row * WBSTR2 + 64 + g * 8];
        f32x4 cacc[4];
        #pragma unroll
        for (int n = 0; n < 4; ++n) {
            int c = n * 16 + li;
            bf16x8 b0 = *(const bf16x8*)&winT[c * TSTR2 + g * 8];
            bf16x8 b1 = *(const bf16x8*)&winT[c * TSTR2 + 32 + g * 8];
            bf16x8 b2 = *(const bf16x8*)&winT[c * TSTR2 + 64 + g * 8];
            f32x4 z = {0.f, 0.f, 0.f, 0.f};
            z = __builtin_amdgcn_mfma_f32_16x16x32_bf16(wa0, b0, z, 0, 0, 0);
            z = __builtin_amdgcn_mfma_f32_16x16x32_bf16(wa1, b1, z, 0, 0, 0);
            z = __builtin_amdgcn_mfma_f32_16x16x32_bf16(wa2, b2, z, 0, 0, 0);
            cacc[n] = z;
        }
        #pragma unroll
        for (int n = 0; n < 4; ++n)
            #pragma unroll
            for (int r = 0; r < 4; ++r)
                pcs[(wv * 16 + g * 4 + r) * PCSS + n * 16 + li] =
                    f2bf(cacc[n][r]);
    }
    __syncthreads();

    // ---- phase 5: coalesced store ----
    {
        int tok = tid >> 2, j0 = (tid & 3) * 16;
        u16x8 v0 = *(const u16x8*)&pcs[tok * PCSS + j0];
        u16x8 v1 = *(const u16x8*)&pcs[tok * PCSS + j0 + 8];
        unsigned short* o = conv + (size_t)(b * LL + t0 + tok) * DD + h * DH + j0;
        *(u16x8*)&o[0] = v0;
        *(u16x8*)&o[8] = v1;
    }
}

// ---- W_fc f32 -> bf16 cast (2MB) + wpeT prep (block 1024) -----------------
__global__ __launch_bounds__(256)
void cvt_kernel(const float* __restrict__ in, unsigned short* __restrict__ out,
                const float* __restrict__ W_pe, unsigned short* __restrict__ wpeT) {
    if (blockIdx.x == 1024) {
        for (int i = threadIdx.x; i < 64 * WPESTR2; i += 256) {
            int c = i / WPESTR2, d = i - c * WPESTR2;
            float v = (c < 2 * KK && d < 64) ? W_pe[d * (2 * KK) + c] : 0.f;
            wpeT[i] = f2bf(v);
        }
        return;
    }
    int i = (blockIdx.x * 256 + threadIdx.x) * 4;
    float4 v = *(const float4*)&in[i];
    ushort4 o;
    o.x = f2bf(v.x); o.y = f2bf(v.y); o.z = f2bf(v.z); o.w = f2bf(v.w);
    *(ushort4*)&out[i] = o;
}

// ---- v = conv @ W_fc^T + x : 256x256 tile, 8 waves, BK=64, XOR-swizzled
//      LDS, double-buffered, 4 phases/K-tile with COUNTED vmcnt matched to
//      first-use (r16 schedule, best measured). f32 X residual. -------------
#define WAITV0() do { asm volatile("s_waitcnt vmcnt(0)" ::: "memory"); \
                      __builtin_amdgcn_sched_barrier(0); } while (0)
#define WAITV2() do { asm volatile("s_waitcnt vmcnt(2)" ::: "memory"); \
                      __builtin_amdgcn_sched_barrier(0); } while (0)
#define WAITV4() do { asm volatile("s_waitcnt vmcnt(4)" ::: "memory"); \
                      __builtin_amdgcn_sched_barrier(0); } while (0)
#define LGK0()   do { asm volatile("s_waitcnt lgkmcnt(0)" ::: "memory"); \
                      __builtin_amdgcn_sched_barrier(0); } while (0)
#define BAR()    do { __builtin_amdgcn_sched_barrier(0); \
                      __builtin_amdgcn_s_barrier(); \
                      __builtin_amdgcn_sched_barrier(0); } while (0)

__global__ __launch_bounds__(512, 2)
void gemm_mfma_kernel(const unsigned short* __restrict__ A,
                      const unsigned short* __restrict__ Bt,
                      const float* __restrict__ X,
                      unsigned short* __restrict__ Vb)
{
    __shared__ __align__(16) unsigned short As0[256 * 64];   // 32 KB each
    __shared__ __align__(16) unsigned short Bs0[256 * 64];
    __shared__ __align__(16) unsigned short As1[256 * 64];
    __shared__ __align__(16) unsigned short Bs1[256 * 64];
    int tid = threadIdx.x;
    int wv = tid >> 6, ln = tid & 63;
    int bid = blockIdx.x;
    int nbid = (bid & 7) * 32 + (bid >> 3);   // XCD-contiguous (256%8==0)
    int bm0 = (nbid >> 2) * 256;              // 64 m-tiles
    int bn0 = (nbid & 3) * 256;               // 4 n-tiles
    int wr = wv >> 2, wc = wv & 3;            // 2x4 wave grid

    // load i covers quarter i (rows i*64..i*64+63) of the 256-row panel
    const unsigned short* ga[4];
    const unsigned short* gb[4];
    int ldo[4];
    #pragma unroll
    for (int i = 0; i < 4; ++i) {
        int dci = i * 512 + wv * 64 + ln;     // dest chunk index (16B units)
        int row = dci >> 3, ch = dci & 7;
        int sc = ch ^ (row & 7);
        ga[i] = A  + (size_t)(bm0 + row) * 1024 + sc * 8;
        gb[i] = Bt + (size_t)(bn0 + row) * 1024 + sc * 8;
        ldo[i] = dci * 8;                      // u16 offset, linear dest
    }

    f32x4 acc[8][4] = {};
    int la = wr * 128 + (ln & 15);
    int lb = wc * 64 + (ln & 15);
    int kg = ln >> 4;                          // 0..3

#define READ_BFR(RB)                                                          \
    _Pragma("unroll")                                                         \
    for (int n = 0; n < 4; ++n)                                               \
      _Pragma("unroll")                                                       \
      for (int ks = 0; ks < 2; ++ks) {                                        \
        int row = lb + n * 16;                                                \
        bfr[n][ks] = *(const bf16x8*)&RB[row * 64 +                           \
                        (((kg + ks * 4) ^ (row & 7)) * 8)];                   \
      }

#define READ_AF(RA, MQ)                                                       \
    _Pragma("unroll")                                                         \
    for (int mm = 0; mm < 2; ++mm)                                            \
      _Pragma("unroll")                                                       \
      for (int ks = 0; ks < 2; ++ks) {                                        \
        int row = la + ((MQ) * 2 + mm) * 16;                                  \
        af[mm][ks] = *(const bf16x8*)&RA[row * 64 +                           \
                        (((kg + ks * 4) ^ (row & 7)) * 8)];                   \
      }

#define MFMAQ(MQ)                                                             \
    __builtin_amdgcn_s_setprio(1);                                            \
    _Pragma("unroll")                                                         \
    for (int mm = 0; mm < 2; ++mm)                                            \
      _Pragma("unroll")                                                       \
      for (int n = 0; n < 4; ++n)                                             \
        _Pragma("unroll")                                                     \
        for (int ks = 0; ks < 2; ++ks)                                        \
          acc[(MQ) * 2 + mm][n] = __builtin_amdgcn_mfma_f32_16x16x32_bf16(    \
              af[mm][ks], bfr[n][ks], acc[(MQ) * 2 + mm][n], 0, 0, 0);        \
    __builtin_amdgcn_s_setprio(0);

    // prologue: stage tile 0 -> buf0 in first-use order
    gload_lds16(gb[0], Bs0 + ldo[0]);
    gload_lds16(gb[1], Bs0 + ldo[1]);
    gload_lds16(gb[2], Bs0 + ldo[2]);
    gload_lds16(gb[3], Bs0 + ldo[3]);
    gload_lds16(ga[0], As0 + ldo[0]);
    gload_lds16(ga[2], As0 + ldo[2]);
    gload_lds16(ga[1], As0 + ldo[1]);
    gload_lds16(ga[3], As0 + ldo[3]);
    WAITV2(); BAR();   // B + even-A published; odd-A (2) still in flight

    unsigned short* Ac = As0; unsigned short* Bc = Bs0;
    unsigned short* An = As1; unsigned short* Bn = Bs1;
    for (int t = 0; t < 16; ++t) {
        int ktn = (t + 1) * 64;
        bool last = (t == 15);
        bf16x8 bfr[4][2], af[2][2];
        // ---- phase 0: bfr + af-q0 (even A-quarter); stage gb'[0..1] ----
        READ_BFR(Bc); READ_AF(Ac, 0);
        if (!last) { gload_lds16(gb[0] + ktn, Bn + ldo[0]);
                     gload_lds16(gb[1] + ktn, Bn + ldo[1]); }
        BAR(); LGK0();
        MFMAQ(0);
        BAR();
        // ---- phase 1: af-q1 (even A-quarter); stage gb'[2..3];
        //      then ensure this tile's odd A-quarters landed ----
        READ_AF(Ac, 1);
        if (!last) { gload_lds16(gb[2] + ktn, Bn + ldo[2]);
                     gload_lds16(gb[3] + ktn, Bn + ldo[3]); }
        BAR(); LGK0();
        MFMAQ(1);
        if (last) { WAITV0(); } else { WAITV4(); }
        BAR();
        // ---- phase 2: af-q2 (odd A-quarter); stage ga'[0],ga'[2] ----
        READ_AF(Ac, 2);
        if (!last) { gload_lds16(ga[0] + ktn, An + ldo[0]);
                     gload_lds16(ga[2] + ktn, An + ldo[2]); }
        BAR(); LGK0();
        MFMAQ(2);
        BAR();
        // ---- phase 3: af-q3 (odd A-quarter); stage ga'[1],ga'[3];
        //      then ensure next tile's B + even-A landed ----
        READ_AF(Ac, 3);
        if (!last) { gload_lds16(ga[1] + ktn, An + ldo[1]);
                     gload_lds16(ga[3] + ktn, An + ldo[3]); }
        BAR(); LGK0();
        MFMAQ(3);
        if (!last) WAITV2();
        BAR();
        // swap buffers
        unsigned short* tA = Ac; Ac = An; An = tA;
        unsigned short* tB = Bc; Bc = Bn; Bn = tB;
    }
#undef READ_BFR
#undef READ_AF
#undef MFMAQ

    // epilogue: v = acc + X, store bf16
    int rb0 = bm0 + wr * 128 + (ln >> 4) * 4;
    int cb0 = bn0 + wc * 64 + (ln & 15);
    #pragma unroll
    for (int m = 0; m < 8; ++m) {
        #pragma unroll
        for (int r = 0; r < 4; ++r) {
            int row = rb0 + m * 16 + r;
            size_t off = (size_t)row * 1024 + cb0;
            #pragma unroll
            for (int n = 0; n < 4; ++n)
                Vb[off + n * 16] = f2bf(acc[m][n][r] + X[off + n * 16]);
        }
    }
}

// ---------------- LayerNorm from bf16 V (row reduce + apply) ---------------
__global__ __launch_bounds__(256)
void ln_kernel(const unsigned short* __restrict__ Vb,
               const float* __restrict__ gamma,
               const float* __restrict__ beta,
               float* __restrict__ out) {
    __shared__ float red[8];
    int row = blockIdx.x;
    int tid = threadIdx.x;
    ushort4 vu = *(const ushort4*)&Vb[(size_t)row * 1024 + tid * 4];
    float v0 = bf2f(vu.x), v1 = bf2f(vu.y), v2 = bf2f(vu.z), v3 = bf2f(vu.w);
    float s = v0 + v1 + v2 + v3;
    float s2 = v0 * v0 + v1 * v1 + v2 * v2 + v3 * v3;
    #pragma unroll
    for (int off = 32; off; off >>= 1) {
        s  += __shfl_xor(s, off, 64);
        s2 += __shfl_xor(s2, off, 64);
    }
    if ((tid & 63) == 0) { red[(tid >> 6) * 2] = s; red[(tid >> 6) * 2 + 1] = s2; }
    __syncthreads();
    s  = red[0] + red[2] + red[4] + red[6];
    s2 = red[1] + red[3] + red[5] + red[7];
    float mu = s * (1.f / 1024.f);
    float var = s2 * (1.f / 1024.f) - mu * mu;
    float rs = rsqrtf(var + 1e-6f);
    float4 g  = *(const float4*)&gamma[tid * 4];
    float4 be = *(const float4*)&beta[tid * 4];
    float4 o = make_float4((v0 - mu) * rs * g.x + be.x,
                           (v1 - mu) * rs * g.y + be.y,
                           (v2 - mu) * rs * g.z + be.z,
                           (v3 - mu) * rs * g.w + be.w);
    *(float4*)&out[(size_t)row * 1024 + tid * 4] = o;
}

extern "C" void kernel_launch(void* const* d_in, const int* in_sizes, int n_in,
                              void* d_out, int out_size, void* d_ws, size_t ws_size,
                              hipStream_t stream) {
    const float* x     = (const float*)d_in[0];
    const float* W_pe  = (const float*)d_in[1];
    const float* b_pe  = (const float*)d_in[2];
    const float* stt   = (const float*)d_in[3];
    const float* W_fc  = (const float*)d_in[4];
    const float* gamma = (const float*)d_in[5];
    const float* beta  = (const float*)d_in[6];
    float* out = (float*)d_out;

    char* ws = (char*)d_ws;
    unsigned short* Vb    = (unsigned short*)ws;                               // 32 MB
    unsigned short* avgT  = (unsigned short*)(ws + (size_t)32 * 1024 * 1024);  // 32.5 MB
    unsigned short* convb = (unsigned short*)(ws + (size_t)68 * 1024 * 1024);  // 32 MB
    unsigned short* wfcb  = (unsigned short*)(ws + (size_t)100 * 1024 * 1024); //  2 MB
    unsigned short* wpeT  = (unsigned short*)(ws + (size_t)102 * 1024 * 1024); //  9 KB
    float*          segs  = (float*)(ws + (size_t)103 * 1024 * 1024);          //  1 MB

    seg_sum_kernel<<<256, 256, 0, stream>>>(x, segs);
    avg_kernel<<<256, 256, 0, stream>>>(x, segs, avgT);
    cvt_kernel<<<1025, 256, 0, stream>>>(W_fc, wfcb, W_pe, wpeT);
    conv_kernel<<<4096, 256, 0, stream>>>(avgT, wpeT, b_pe, stt, convb);
    gemm_mfma_kernel<<<256, 512, 0, stream>>>(convb, wfcb, x, Vb);
    ln_kernel<<<16384, 256, 0, stream>>>(Vb, gamma, beta, out);
}

// Round 20
// 141.718 us; speedup vs baseline: 1.1007x; 1.0394x over previous
//
#include <hip/hip_runtime.h>
#include <math.h>

// Problem constants (B,L,D,H,K) = (8, 2048, 1024, 16, 31)
#define BB 8
#define LL 2048
#define DD 1024
#define HH 16
#define DH 64          // D/H
#define KK 31
#define NSEG 32
#define SEGLEN 64      // LL/NSEG

#define TLEN 64        // tokens per conv block
#define TROW 2080      // avgT row stride (u16): 32-zero prefix + 2048 tokens
#define TSTR2 112      // winT row stride (u16): 14 chunks of 16B
#define WBSTR2 104     // wband row stride (u16): 208B
#define WPESTR2 72     // wpeT row stride (u16): 144B
#define PCSS 64        // pcs row stride (u16): row-internal accesses only

typedef __attribute__((ext_vector_type(8))) short bf16x8;
typedef __attribute__((ext_vector_type(4))) float f32x4;
typedef __attribute__((ext_vector_type(8))) unsigned short u16x8;

__device__ __forceinline__ unsigned short f2bf(float f) {
    unsigned u = __float_as_uint(f);
    unsigned r = (u + 0x7fffu + ((u >> 16) & 1u)) >> 16;   // RNE
    return (unsigned short)r;
}
__device__ __forceinline__ float bf2f(unsigned short s) {
    return __uint_as_float(((unsigned)s) << 16);
}

__device__ __forceinline__ void gload_lds16(const void* g, void* l) {
    __builtin_amdgcn_global_load_lds(
        (const __attribute__((address_space(1))) void*)g,
        (__attribute__((address_space(3))) void*)l, 16, 0, 0);
}

// ---------------- Pass 1a: per-segment sums (for parallel cumsum) ----------
__global__ __launch_bounds__(256)
void seg_sum_kernel(const float* __restrict__ x, float* __restrict__ segsum) {
    int g = blockIdx.x * 256 + threadIdx.x;   // B*NSEG*D threads
    int d = g & (DD - 1);
    int s = (g >> 10) & (NSEG - 1);
    int b = g >> 15;
    const float* p = x + (size_t)(b * LL + s * SEGLEN) * DD + d;
    float acc = 0.f;
    #pragma unroll 8
    for (int i = 0; i < SEGLEN; ++i) acc += p[(size_t)i * DD];
    segsum[g] = acc;   // layout [b][s][d] == flat g
}

// ---- Pass 1b: running mean -> avgT [b,h,d][32zero|2048] only --------------
__global__ __launch_bounds__(256)
void avg_kernel(const float* __restrict__ x, const float* __restrict__ segsum,
                unsigned short* __restrict__ avgT) {
    int g = blockIdx.x * 256 + threadIdx.x;
    int d = g & (DD - 1);
    int s = (g >> 10) & (NSEG - 1);
    int b = g >> 15;
    float run = 0.f;
    const float* ss = segsum + ((size_t)b << 15) + d;
    for (int s2 = 0; s2 < s; ++s2) run += ss[s2 << 10];
    const float* p = x + (size_t)(b * LL + s * SEGLEN) * DD + d;
    unsigned short* rowt = avgT +
        ((size_t)(b * HH + (d >> 6)) * DH + (d & 63)) * TROW;
    unsigned short* qt = rowt + 32 + s * SEGLEN;
    if (s == 0) {   // zero the 32-token prefix (window padding)
        u16x8 z = {};
        #pragma unroll
        for (int j = 0; j < 4; ++j) *(u16x8*)&rowt[j * 8] = z;
    }
    int t0 = s * SEGLEN;
    #pragma unroll
    for (int j = 0; j < 8; ++j) {
        u16x8 v;
        #pragma unroll
        for (int e = 0; e < 8; ++e) {
            int i = j * 8 + e;
            run += p[(size_t)i * DD];
            v[e] = f2bf(run / (float)(t0 + i + 1));
        }
        *(u16x8*)&qt[j * 8] = v;
    }
}

// ------- Fused: pc = ci@W_pe+b_pe -> gated energy -> softmax -> local conv --
// Grid is XCD-swizzled by the launcher mapping below (4096 % 8 == 0).
__global__ __launch_bounds__(256, 4)
void conv_kernel(const unsigned short* __restrict__ avgT,
                 const unsigned short* __restrict__ wpeT,
                 const float* __restrict__ b_pe, const float* __restrict__ stt,
                 unsigned short* __restrict__ conv) {
    __shared__ __align__(16) unsigned short pcs[64 * PCSS];     //  8192 B
    __shared__ __align__(16) unsigned short winT[64 * TSTR2];   // 14336 B
    __shared__ __align__(16) unsigned short wub[64 * WBSTR2];   // 13312 B

    int tid = threadIdx.x;
    // XCD-aware bijective swizzle: each XCD gets contiguous 512-block chunks
    // (= 16 complete (b,h) panels) for avgT L2 locality.
    int bidl = (blockIdx.x & 7) * 512 + (blockIdx.x >> 3);
    int tile = bidl & 31;
    int bh = bidl >> 5;
    int b = bh >> 4, h = bh & 15;
    int t0 = tile * TLEN;
    int wv = tid >> 6, ln = tid & 63;
    int g = ln >> 4, li = ln & 15;

    // ---- phase 0: async staging (all global_load_lds width 16) ----
    {
        const unsigned short* gT = avgT + (size_t)(b * HH + h) * DH * TROW;
        #pragma unroll
        for (int q = 0; q < 3; ++q) {
            int i = tid + q * 256;
            int d = i / 14, c = i - d * 14;
            gload_lds16(gT + (size_t)d * TROW + t0 + c * 8, winT + (i & ~63) * 8);
        }
        if (tid < 128) {
            int i = 768 + tid;
            int d = i / 14, c = i - d * 14;
            gload_lds16(gT + (size_t)d * TROW + t0 + c * 8, winT + (i & ~63) * 8);
        }
        #pragma unroll
        for (int q = 0; q < 2; ++q) {
            int i = tid + q * 256;
            gload_lds16(wpeT + i * 8, wub + (i & ~63) * 8);
        }
        if (tid < 64) {
            int i = 512 + tid;
            gload_lds16(wpeT + i * 8, wub + (i & ~63) * 8);
        }
    }
    __syncthreads();

    // ---- phase 1: pc = ci @ W_pe via MFMA (A gathered from winT cols) ----
    f32x4 pacc[4];
    {
        int q32 = 32 + wv * 16 + li;   // window col of this token
        bf16x8 a0, a1;
        #pragma unroll
        for (int e = 0; e < 8; ++e) {
            a0[e] = (short)winT[(g * 8 + e) * TSTR2 + q32];
            a1[e] = (short)winT[(32 + g * 8 + e) * TSTR2 + q32];
        }
        #pragma unroll
        for (int n = 0; n < 4; ++n) {
            int c = n * 16 + li;
            bf16x8 b0 = *(const bf16x8*)&wub[c * WPESTR2 + g * 8];
            bf16x8 b1 = *(const bf16x8*)&wub[c * WPESTR2 + 32 + g * 8];
            f32x4 z = {0.f, 0.f, 0.f, 0.f};
            z = __builtin_amdgcn_mfma_f32_16x16x32_bf16(a0, b0, z, 0, 0, 0);
            z = __builtin_amdgcn_mfma_f32_16x16x32_bf16(a1, b1, z, 0, 0, 0);
            pacc[n] = z;
        }
    }
    __syncthreads();   // wpeT reads done; wub becomes wband below

    {   // pcs writes + zero wband (overlay wpeT)
        #pragma unroll
        for (int n = 0; n < 4; ++n) {
            int c = n * 16 + li;
            float bp = (c < 2 * KK) ? b_pe[c] : 0.f;
            #pragma unroll
            for (int r = 0; r < 4; ++r)
                pcs[(wv * 16 + g * 4 + r) * PCSS + c] = f2bf(pacc[n][r] + bp);
        }
        for (int i = tid; i < 64 * WBSTR2 / 8; i += 256) {
            u16x8 z = {};
            *(u16x8*)&wub[i * 8] = z;
        }
    }
    __syncthreads();

    // ---- phase 3: softmax (no max-reduce; energies bounded) -> wband ----
    {
        int half = ln >> 5, k = ln & 31;
        int kc = (k < KK) ? k : 0;
        float sttk = stt[h * KK + kc];
        for (int it = 0; it < 8; ++it) {
            int tok = wv * 16 + it * 2 + half;
            float dyn  = bf2f(pcs[tok * PCSS + kc]);
            float gate = bf2f(pcs[tok * PCSS + KK + kc]);
            float e = 0.f;
            if (k < KK) e = __expf(sttk + dyn / (1.f + __expf(-gate)));
            float sum = e;
            #pragma unroll
            for (int off = 16; off; off >>= 1) sum += __shfl_xor(sum, off, 64);
            float wvl = e / sum;
            if (k < KK && t0 + tok + k >= KK - 1)
                wub[tok * WBSTR2 + tok + k + 2] = f2bf(wvl);
        }
    }
    __syncthreads();

    // ---- phase 4: conv = wband @ winT^T via MFMA (K = 96) ----
    {
        int row = wv * 16 + li;
        bf16x8 wa0 = *(const bf16x8*)&wub[row * WBSTR2 + g * 8];
        bf16x8 wa1 = *(const bf16x8*)&wub[row * WBSTR2 + 32 + g * 8];
        bf16x8 wa2 = *(const bf16x8*)&wub[row * WBSTR2 + 64 + g * 8];
        f32x4 cacc[4];
        #pragma unroll
        for (int n = 0; n < 4; ++n) {
            int c = n * 16 + li;
            bf16x8 b0 = *(const bf16x8*)&winT[c * TSTR2 + g * 8];
            bf16x8 b1 = *(const bf16x8*)&winT[c * TSTR2 + 32 + g * 8];
            bf16x8 b2 = *(const bf16x8*)&winT[c * TSTR2 + 64 + g * 8];
            f32x4 z = {0.f, 0.f, 0.f, 0.f};
            z = __builtin_amdgcn_mfma_f32_16x16x32_bf16(wa0, b0, z, 0, 0, 0);
            z = __builtin_amdgcn_mfma_f32_16x16x32_bf16(wa1, b1, z, 0, 0, 0);
            z = __builtin_amdgcn_mfma_f32_16x16x32_bf16(wa2, b2, z, 0, 0, 0);
            cacc[n] = z;
        }
        #pragma unroll
        for (int n = 0; n < 4; ++n)
            #pragma unroll
            for (int r = 0; r < 4; ++r)
                pcs[(wv * 16 + g * 4 + r) * PCSS + n * 16 + li] =
                    f2bf(cacc[n][r]);
    }
    __syncthreads();

    // ---- phase 5: coalesced store ----
    {
        int tok = tid >> 2, j0 = (tid & 3) * 16;
        u16x8 v0 = *(const u16x8*)&pcs[tok * PCSS + j0];
        u16x8 v1 = *(const u16x8*)&pcs[tok * PCSS + j0 + 8];
        unsigned short* o = conv + (size_t)(b * LL + t0 + tok) * DD + h * DH + j0;
        *(u16x8*)&o[0] = v0;
        *(u16x8*)&o[8] = v1;
    }
}

// ---- W_fc f32 -> bf16 cast (2MB) + wpeT prep (block 1024) -----------------
__global__ __launch_bounds__(256)
void cvt_kernel(const float* __restrict__ in, unsigned short* __restrict__ out,
                const float* __restrict__ W_pe, unsigned short* __restrict__ wpeT) {
    if (blockIdx.x == 1024) {
        for (int i = threadIdx.x; i < 64 * WPESTR2; i += 256) {
            int c = i / WPESTR2, d = i - c * WPESTR2;
            float v = (c < 2 * KK && d < 64) ? W_pe[d * (2 * KK) + c] : 0.f;
            wpeT[i] = f2bf(v);
        }
        return;
    }
    int i = (blockIdx.x * 256 + threadIdx.x) * 4;
    float4 v = *(const float4*)&in[i];
    ushort4 o;
    o.x = f2bf(v.x); o.y = f2bf(v.y); o.z = f2bf(v.z); o.w = f2bf(v.w);
    *(ushort4*)&out[i] = o;
}

// ---- v = conv @ W_fc^T + x : 256x256 tile, 8 waves, BK=64, XOR-swizzled
//      LDS, double-buffered, 4 phases/K-tile with COUNTED vmcnt matched to
//      first-use (r16 schedule, best measured). f32 X residual. -------------
#define WAITV0() do { asm volatile("s_waitcnt vmcnt(0)" ::: "memory"); \
                      __builtin_amdgcn_sched_barrier(0); } while (0)
#define WAITV2() do { asm volatile("s_waitcnt vmcnt(2)" ::: "memory"); \
                      __builtin_amdgcn_sched_barrier(0); } while (0)
#define WAITV4() do { asm volatile("s_waitcnt vmcnt(4)" ::: "memory"); \
                      __builtin_amdgcn_sched_barrier(0); } while (0)
#define LGK0()   do { asm volatile("s_waitcnt lgkmcnt(0)" ::: "memory"); \
                      __builtin_amdgcn_sched_barrier(0); } while (0)
#define BAR()    do { __builtin_amdgcn_sched_barrier(0); \
                      __builtin_amdgcn_s_barrier(); \
                      __builtin_amdgcn_sched_barrier(0); } while (0)

__global__ __launch_bounds__(512, 2)
void gemm_mfma_kernel(const unsigned short* __restrict__ A,
                      const unsigned short* __restrict__ Bt,
                      const float* __restrict__ X,
                      unsigned short* __restrict__ Vb)
{
    __shared__ __align__(16) unsigned short As0[256 * 64];   // 32 KB each
    __shared__ __align__(16) unsigned short Bs0[256 * 64];
    __shared__ __align__(16) unsigned short As1[256 * 64];
    __shared__ __align__(16) unsigned short Bs1[256 * 64];
    int tid = threadIdx.x;
    int wv = tid >> 6, ln = tid & 63;
    int bid = blockIdx.x;
    int nbid = (bid & 7) * 32 + (bid >> 3);   // XCD-contiguous (256%8==0)
    int bm0 = (nbid >> 2) * 256;              // 64 m-tiles
    int bn0 = (nbid & 3) * 256;               // 4 n-tiles
    int wr = wv >> 2, wc = wv & 3;            // 2x4 wave grid

    // load i covers quarter i (rows i*64..i*64+63) of the 256-row panel
    const unsigned short* ga[4];
    const unsigned short* gb[4];
    int ldo[4];
    #pragma unroll
    for (int i = 0; i < 4; ++i) {
        int dci = i * 512 + wv * 64 + ln;     // dest chunk index (16B units)
        int row = dci >> 3, ch = dci & 7;
        int sc = ch ^ (row & 7);
        ga[i] = A  + (size_t)(bm0 + row) * 1024 + sc * 8;
        gb[i] = Bt + (size_t)(bn0 + row) * 1024 + sc * 8;
        ldo[i] = dci * 8;                      // u16 offset, linear dest
    }

    f32x4 acc[8][4] = {};
    int la = wr * 128 + (ln & 15);
    int lb = wc * 64 + (ln & 15);
    int kg = ln >> 4;                          // 0..3

#define READ_BFR(RB)                                                          \
    _Pragma("unroll")                                                         \
    for (int n = 0; n < 4; ++n)                                               \
      _Pragma("unroll")                                                       \
      for (int ks = 0; ks < 2; ++ks) {                                        \
        int row = lb + n * 16;                                                \
        bfr[n][ks] = *(const bf16x8*)&RB[row * 64 +                           \
                        (((kg + ks * 4) ^ (row & 7)) * 8)];                   \
      }

#define READ_AF(RA, MQ)                                                       \
    _Pragma("unroll")                                                         \
    for (int mm = 0; mm < 2; ++mm)                                            \
      _Pragma("unroll")                                                       \
      for (int ks = 0; ks < 2; ++ks) {                                        \
        int row = la + ((MQ) * 2 + mm) * 16;                                  \
        af[mm][ks] = *(const bf16x8*)&RA[row * 64 +                           \
                        (((kg + ks * 4) ^ (row & 7)) * 8)];                   \
      }

#define MFMAQ(MQ)                                                             \
    __builtin_amdgcn_s_setprio(1);                                            \
    _Pragma("unroll")                                                         \
    for (int mm = 0; mm < 2; ++mm)                                            \
      _Pragma("unroll")                                                       \
      for (int n = 0; n < 4; ++n)                                             \
        _Pragma("unroll")                                                     \
        for (int ks = 0; ks < 2; ++ks)                                        \
          acc[(MQ) * 2 + mm][n] = __builtin_amdgcn_mfma_f32_16x16x32_bf16(    \
              af[mm][ks], bfr[n][ks], acc[(MQ) * 2 + mm][n], 0, 0, 0);        \
    __builtin_amdgcn_s_setprio(0);

    // prologue: stage tile 0 -> buf0 in first-use order
    gload_lds16(gb[0], Bs0 + ldo[0]);
    gload_lds16(gb[1], Bs0 + ldo[1]);
    gload_lds16(gb[2], Bs0 + ldo[2]);
    gload_lds16(gb[3], Bs0 + ldo[3]);
    gload_lds16(ga[0], As0 + ldo[0]);
    gload_lds16(ga[2], As0 + ldo[2]);
    gload_lds16(ga[1], As0 + ldo[1]);
    gload_lds16(ga[3], As0 + ldo[3]);
    WAITV2(); BAR();   // B + even-A published; odd-A (2) still in flight

    unsigned short* Ac = As0; unsigned short* Bc = Bs0;
    unsigned short* An = As1; unsigned short* Bn = Bs1;
    for (int t = 0; t < 16; ++t) {
        int ktn = (t + 1) * 64;
        bool last = (t == 15);
        bf16x8 bfr[4][2], af[2][2];
        // ---- phase 0: bfr + af-q0 (even A-quarter); stage gb'[0..1] ----
        READ_BFR(Bc); READ_AF(Ac, 0);
        if (!last) { gload_lds16(gb[0] + ktn, Bn + ldo[0]);
                     gload_lds16(gb[1] + ktn, Bn + ldo[1]); }
        BAR(); LGK0();
        MFMAQ(0);
        BAR();
        // ---- phase 1: af-q1 (even A-quarter); stage gb'[2..3];
        //      then ensure this tile's odd A-quarters landed ----
        READ_AF(Ac, 1);
        if (!last) { gload_lds16(gb[2] + ktn, Bn + ldo[2]);
                     gload_lds16(gb[3] + ktn, Bn + ldo[3]); }
        BAR(); LGK0();
        MFMAQ(1);
        if (last) { WAITV0(); } else { WAITV4(); }
        BAR();
        // ---- phase 2: af-q2 (odd A-quarter); stage ga'[0],ga'[2] ----
        READ_AF(Ac, 2);
        if (!last) { gload_lds16(ga[0] + ktn, An + ldo[0]);
                     gload_lds16(ga[2] + ktn, An + ldo[2]); }
        BAR(); LGK0();
        MFMAQ(2);
        BAR();
        // ---- phase 3: af-q3 (odd A-quarter); stage ga'[1],ga'[3];
        //      then ensure next tile's B + even-A landed ----
        READ_AF(Ac, 3);
        if (!last) { gload_lds16(ga[1] + ktn, An + ldo[1]);
                     gload_lds16(ga[3] + ktn, An + ldo[3]); }
        BAR(); LGK0();
        MFMAQ(3);
        if (!last) WAITV2();
        BAR();
        // swap buffers
        unsigned short* tA = Ac; Ac = An; An = tA;
        unsigned short* tB = Bc; Bc = Bn; Bn = tB;
    }
#undef READ_BFR
#undef READ_AF
#undef MFMAQ

    // epilogue: v = acc + X, store bf16
    int rb0 = bm0 + wr * 128 + (ln >> 4) * 4;
    int cb0 = bn0 + wc * 64 + (ln & 15);
    #pragma unroll
    for (int m = 0; m < 8; ++m) {
        #pragma unroll
        for (int r = 0; r < 4; ++r) {
            int row = rb0 + m * 16 + r;
            size_t off = (size_t)row * 1024 + cb0;
            #pragma unroll
            for (int n = 0; n < 4; ++n)
                Vb[off + n * 16] = f2bf(acc[m][n][r] + X[off + n * 16]);
        }
    }
}

// ---------------- LayerNorm from bf16 V (row reduce + apply) ---------------
__global__ __launch_bounds__(256)
void ln_kernel(const unsigned short* __restrict__ Vb,
               const float* __restrict__ gamma,
               const float* __restrict__ beta,
               float* __restrict__ out) {
    __shared__ float red[8];
    int row = blockIdx.x;
    int tid = threadIdx.x;
    ushort4 vu = *(const ushort4*)&Vb[(size_t)row * 1024 + tid * 4];
    float v0 = bf2f(vu.x), v1 = bf2f(vu.y), v2 = bf2f(vu.z), v3 = bf2f(vu.w);
    float s = v0 + v1 + v2 + v3;
    float s2 = v0 * v0 + v1 * v1 + v2 * v2 + v3 * v3;
    #pragma unroll
    for (int off = 32; off; off >>= 1) {
        s  += __shfl_xor(s, off, 64);
        s2 += __shfl_xor(s2, off, 64);
    }
    if ((tid & 63) == 0) { red[(tid >> 6) * 2] = s; red[(tid >> 6) * 2 + 1] = s2; }
    __syncthreads();
    s  = red[0] + red[2] + red[4] + red[6];
    s2 = red[1] + red[3] + red[5] + red[7];
    float mu = s * (1.f / 1024.f);
    float var = s2 * (1.f / 1024.f) - mu * mu;
    float rs = rsqrtf(var + 1e-6f);
    float4 g  = *(const float4*)&gamma[tid * 4];
    float4 be = *(const float4*)&beta[tid * 4];
    float4 o = make_float4((v0 - mu) * rs * g.x + be.x,
                           (v1 - mu) * rs * g.y + be.y,
                           (v2 - mu) * rs * g.z + be.z,
                           (v3 - mu) * rs * g.w + be.w);
    *(float4*)&out[(size_t)row * 1024 + tid * 4] = o;
}

extern "C" void kernel_launch(void* const* d_in, const int* in_sizes, int n_in,
                              void* d_out, int out_size, void* d_ws, size_t ws_size,
                              hipStream_t stream) {
    const float* x     = (const float*)d_in[0];
    const float* W_pe  = (const float*)d_in[1];
    const float* b_pe  = (const float*)d_in[2];
    const float* stt   = (const float*)d_in[3];
    const float* W_fc  = (const float*)d_in[4];
    const float* gamma = (const float*)d_in[5];
    const float* beta  = (const float*)d_in[6];
    float* out = (float*)d_out;

    char* ws = (char*)d_ws;
    unsigned short* Vb    = (unsigned short*)ws;                               // 32 MB
    unsigned short* avgT  = (unsigned short*)(ws + (size_t)32 * 1024 * 1024);  // 32.5 MB
    unsigned short* convb = (unsigned short*)(ws + (size_t)68 * 1024 * 1024);  // 32 MB
    unsigned short* wfcb  = (unsigned short*)(ws + (size_t)100 * 1024 * 1024); //  2 MB
    unsigned short* wpeT  = (unsigned short*)(ws + (size_t)102 * 1024 * 1024); //  9 KB
    float*          segs  = (float*)(ws + (size_t)103 * 1024 * 1024);          //  1 MB

    seg_sum_kernel<<<1024, 256, 0, stream>>>(x, segs);
    avg_kernel<<<1024, 256, 0, stream>>>(x, segs, avgT);
    cvt_kernel<<<1025, 256, 0, stream>>>(W_fc, wfcb, W_pe, wpeT);
    conv_kernel<<<4096, 256, 0, stream>>>(avgT, wpeT, b_pe, stt, convb);
    gemm_mfma_kernel<<<256, 512, 0, stream>>>(convb, wfcb, x, Vb);
    ln_kernel<<<16384, 256, 0, stream>>>(Vb, gamma, beta, out);
}

// Round 21
// 141.334 us; speedup vs baseline: 1.1037x; 1.0027x over previous
//
#include <hip/hip_runtime.h>
#include <math.h>

// Problem constants (B,L,D,H,K) = (8, 2048, 1024, 16, 31)
#define BB 8
#define LL 2048
#define DD 1024
#define HH 16
#define DH 64          // D/H
#define KK 31
#define NSEG 32
#define SEGLEN 64      // LL/NSEG

#define TLEN 64        // tokens per conv block
#define TROW 2080      // avgT row stride (u16): 32-zero prefix + 2048 tokens
#define TSTR2 112      // winT row stride (u16): 14 chunks of 16B
#define WBSTR2 104     // wband row stride (u16): 208B
#define WPESTR2 72     // wpeT row stride (u16): 144B
#define PCSS 64        // pcs row stride (u16): row-internal accesses only

typedef __attribute__((ext_vector_type(8))) short bf16x8;
typedef __attribute__((ext_vector_type(4))) float f32x4;
typedef __attribute__((ext_vector_type(8))) unsigned short u16x8;

__device__ __forceinline__ unsigned short f2bf(float f) {
    unsigned u = __float_as_uint(f);
    unsigned r = (u + 0x7fffu + ((u >> 16) & 1u)) >> 16;   // RNE
    return (unsigned short)r;
}
__device__ __forceinline__ float bf2f(unsigned short s) {
    return __uint_as_float(((unsigned)s) << 16);
}

__device__ __forceinline__ void gload_lds16(const void* g, void* l) {
    __builtin_amdgcn_global_load_lds(
        (const __attribute__((address_space(1))) void*)g,
        (__attribute__((address_space(3))) void*)l, 16, 0, 0);
}

// ---------------- Pass 1a: per-segment sums (for parallel cumsum) ----------
__global__ __launch_bounds__(256)
void seg_sum_kernel(const float* __restrict__ x, float* __restrict__ segsum) {
    int g = blockIdx.x * 256 + threadIdx.x;   // B*NSEG*D threads
    int d = g & (DD - 1);
    int s = (g >> 10) & (NSEG - 1);
    int b = g >> 15;
    const float* p = x + (size_t)(b * LL + s * SEGLEN) * DD + d;
    float acc = 0.f;
    #pragma unroll 8
    for (int i = 0; i < SEGLEN; ++i) acc += p[(size_t)i * DD];
    segsum[g] = acc;   // layout [b][s][d] == flat g
}

// ---- Pass 1b: running mean -> avgT [b,h,d][32zero|2048] only --------------
__global__ __launch_bounds__(256)
void avg_kernel(const float* __restrict__ x, const float* __restrict__ segsum,
                unsigned short* __restrict__ avgT) {
    int g = blockIdx.x * 256 + threadIdx.x;
    int d = g & (DD - 1);
    int s = (g >> 10) & (NSEG - 1);
    int b = g >> 15;
    float run = 0.f;
    const float* ss = segsum + ((size_t)b << 15) + d;
    for (int s2 = 0; s2 < s; ++s2) run += ss[s2 << 10];
    const float* p = x + (size_t)(b * LL + s * SEGLEN) * DD + d;
    unsigned short* rowt = avgT +
        ((size_t)(b * HH + (d >> 6)) * DH + (d & 63)) * TROW;
    unsigned short* qt = rowt + 32 + s * SEGLEN;
    if (s == 0) {   // zero the 32-token prefix (window padding)
        u16x8 z = {};
        #pragma unroll
        for (int j = 0; j < 4; ++j) *(u16x8*)&rowt[j * 8] = z;
    }
    int t0 = s * SEGLEN;
    #pragma unroll
    for (int j = 0; j < 8; ++j) {
        u16x8 v;
        #pragma unroll
        for (int e = 0; e < 8; ++e) {
            int i = j * 8 + e;
            run += p[(size_t)i * DD];
            v[e] = f2bf(run / (float)(t0 + i + 1));
        }
        *(u16x8*)&qt[j * 8] = v;
    }
}

// ------- Fused: pc = ci@W_pe+b_pe -> gated energy -> softmax -> local conv --
// Grid is XCD-swizzled by the launcher mapping below (4096 % 8 == 0).
__global__ __launch_bounds__(256, 4)
void conv_kernel(const unsigned short* __restrict__ avgT,
                 const unsigned short* __restrict__ wpeT,
                 const float* __restrict__ b_pe, const float* __restrict__ stt,
                 unsigned short* __restrict__ conv) {
    __shared__ __align__(16) unsigned short pcs[64 * PCSS];     //  8192 B
    __shared__ __align__(16) unsigned short winT[64 * TSTR2];   // 14336 B
    __shared__ __align__(16) unsigned short wub[64 * WBSTR2];   // 13312 B

    int tid = threadIdx.x;
    // XCD-aware bijective swizzle: each XCD gets contiguous 512-block chunks
    // (= 16 complete (b,h) panels) for avgT L2 locality.
    int bidl = (blockIdx.x & 7) * 512 + (blockIdx.x >> 3);
    int tile = bidl & 31;
    int bh = bidl >> 5;
    int b = bh >> 4, h = bh & 15;
    int t0 = tile * TLEN;
    int wv = tid >> 6, ln = tid & 63;
    int g = ln >> 4, li = ln & 15;

    // ---- phase 0: async staging (all global_load_lds width 16) ----
    {
        const unsigned short* gT = avgT + (size_t)(b * HH + h) * DH * TROW;
        #pragma unroll
        for (int q = 0; q < 3; ++q) {
            int i = tid + q * 256;
            int d = i / 14, c = i - d * 14;
            gload_lds16(gT + (size_t)d * TROW + t0 + c * 8, winT + (i & ~63) * 8);
        }
        if (tid < 128) {
            int i = 768 + tid;
            int d = i / 14, c = i - d * 14;
            gload_lds16(gT + (size_t)d * TROW + t0 + c * 8, winT + (i & ~63) * 8);
        }
        #pragma unroll
        for (int q = 0; q < 2; ++q) {
            int i = tid + q * 256;
            gload_lds16(wpeT + i * 8, wub + (i & ~63) * 8);
        }
        if (tid < 64) {
            int i = 512 + tid;
            gload_lds16(wpeT + i * 8, wub + (i & ~63) * 8);
        }
    }
    __syncthreads();

    // ---- phase 1: pc = ci @ W_pe via MFMA (A gathered from winT cols) ----
    f32x4 pacc[4];
    {
        int q32 = 32 + wv * 16 + li;   // window col of this token
        bf16x8 a0, a1;
        #pragma unroll
        for (int e = 0; e < 8; ++e) {
            a0[e] = (short)winT[(g * 8 + e) * TSTR2 + q32];
            a1[e] = (short)winT[(32 + g * 8 + e) * TSTR2 + q32];
        }
        #pragma unroll
        for (int n = 0; n < 4; ++n) {
            int c = n * 16 + li;
            bf16x8 b0 = *(const bf16x8*)&wub[c * WPESTR2 + g * 8];
            bf16x8 b1 = *(const bf16x8*)&wub[c * WPESTR2 + 32 + g * 8];
            f32x4 z = {0.f, 0.f, 0.f, 0.f};
            z = __builtin_amdgcn_mfma_f32_16x16x32_bf16(a0, b0, z, 0, 0, 0);
            z = __builtin_amdgcn_mfma_f32_16x16x32_bf16(a1, b1, z, 0, 0, 0);
            pacc[n] = z;
        }
    }
    __syncthreads();   // wpeT reads done; wub becomes wband below

    {   // pcs writes + zero wband (overlay wpeT)
        #pragma unroll
        for (int n = 0; n < 4; ++n) {
            int c = n * 16 + li;
            float bp = (c < 2 * KK) ? b_pe[c] : 0.f;
            #pragma unroll
            for (int r = 0; r < 4; ++r)
                pcs[(wv * 16 + g * 4 + r) * PCSS + c] = f2bf(pacc[n][r] + bp);
        }
        for (int i = tid; i < 64 * WBSTR2 / 8; i += 256) {
            u16x8 z = {};
            *(u16x8*)&wub[i * 8] = z;
        }
    }
    __syncthreads();

    // ---- phase 3: softmax (no max-reduce; energies bounded) -> wband ----
    {
        int half = ln >> 5, k = ln & 31;
        int kc = (k < KK) ? k : 0;
        float sttk = stt[h * KK + kc];
        for (int it = 0; it < 8; ++it) {
            int tok = wv * 16 + it * 2 + half;
            float dyn  = bf2f(pcs[tok * PCSS + kc]);
            float gate = bf2f(pcs[tok * PCSS + KK + kc]);
            float e = 0.f;
            if (k < KK) e = __expf(sttk + dyn / (1.f + __expf(-gate)));
            float sum = e;
            #pragma unroll
            for (int off = 16; off; off >>= 1) sum += __shfl_xor(sum, off, 64);
            float wvl = e / sum;
            if (k < KK && t0 + tok + k >= KK - 1)
                wub[tok * WBSTR2 + tok + k + 2] = f2bf(wvl);
        }
    }
    __syncthreads();

    // ---- phase 4: conv = wband @ winT^T via MFMA (K = 96) ----
    {
        int row = wv * 16 + li;
        bf16x8 wa0 = *(const bf16x8*)&wub[row * WBSTR2 + g * 8];
        bf16x8 wa1 = *(const bf16x8*)&wub[row * WBSTR2 + 32 + g * 8];
        bf16x8 wa2 = *(const bf16x8*)&wub[row * WBSTR2 + 64 + g * 8];
        f32x4 cacc[4];
        #pragma unroll
        for (int n = 0; n < 4; ++n) {
            int c = n * 16 + li;
            bf16x8 b0 = *(const bf16x8*)&winT[c * TSTR2 + g * 8];
            bf16x8 b1 = *(const bf16x8*)&winT[c * TSTR2 + 32 + g * 8];
            bf16x8 b2 = *(const bf16x8*)&winT[c * TSTR2 + 64 + g * 8];
            f32x4 z = {0.f, 0.f, 0.f, 0.f};
            z = __builtin_amdgcn_mfma_f32_16x16x32_bf16(wa0, b0, z, 0, 0, 0);
            z = __builtin_amdgcn_mfma_f32_16x16x32_bf16(wa1, b1, z, 0, 0, 0);
            z = __builtin_amdgcn_mfma_f32_16x16x32_bf16(wa2, b2, z, 0, 0, 0);
            cacc[n] = z;
        }
        #pragma unroll
        for (int n = 0; n < 4; ++n)
            #pragma unroll
            for (int r = 0; r < 4; ++r)
                pcs[(wv * 16 + g * 4 + r) * PCSS + n * 16 + li] =
                    f2bf(cacc[n][r]);
    }
    __syncthreads();

    // ---- phase 5: coalesced store ----
    {
        int tok = tid >> 2, j0 = (tid & 3) * 16;
        u16x8 v0 = *(const u16x8*)&pcs[tok * PCSS + j0];
        u16x8 v1 = *(const u16x8*)&pcs[tok * PCSS + j0 + 8];
        unsigned short* o = conv + (size_t)(b * LL + t0 + tok) * DD + h * DH + j0;
        *(u16x8*)&o[0] = v0;
        *(u16x8*)&o[8] = v1;
    }
}

// ---- W_fc f32 -> bf16 cast (2MB) + wpeT prep (block 1024) -----------------
__global__ __launch_bounds__(256)
void cvt_kernel(const float* __restrict__ in, unsigned short* __restrict__ out,
                const float* __restrict__ W_pe, unsigned short* __restrict__ wpeT) {
    if (blockIdx.x == 1024) {
        for (int i = threadIdx.x; i < 64 * WPESTR2; i += 256) {
            int c = i / WPESTR2, d = i - c * WPESTR2;
            float v = (c < 2 * KK && d < 64) ? W_pe[d * (2 * KK) + c] : 0.f;
            wpeT[i] = f2bf(v);
        }
        return;
    }
    int i = (blockIdx.x * 256 + threadIdx.x) * 4;
    float4 v = *(const float4*)&in[i];
    ushort4 o;
    o.x = f2bf(v.x); o.y = f2bf(v.y); o.z = f2bf(v.z); o.w = f2bf(v.w);
    *(ushort4*)&out[i] = o;
}

// ---- v = conv @ W_fc^T + x : 256x256 tile, 8 waves, BK=64, XOR-swizzled
//      LDS, double-buffered, 4 phases/K-tile with COUNTED vmcnt matched to
//      first-use (r16 schedule, best measured). f32 X residual. -------------
#define WAITV0() do { asm volatile("s_waitcnt vmcnt(0)" ::: "memory"); \
                      __builtin_amdgcn_sched_barrier(0); } while (0)
#define WAITV2() do { asm volatile("s_waitcnt vmcnt(2)" ::: "memory"); \
                      __builtin_amdgcn_sched_barrier(0); } while (0)
#define WAITV4() do { asm volatile("s_waitcnt vmcnt(4)" ::: "memory"); \
                      __builtin_amdgcn_sched_barrier(0); } while (0)
#define LGK0()   do { asm volatile("s_waitcnt lgkmcnt(0)" ::: "memory"); \
                      __builtin_amdgcn_sched_barrier(0); } while (0)
#define BAR()    do { __builtin_amdgcn_sched_barrier(0); \
                      __builtin_amdgcn_s_barrier(); \
                      __builtin_amdgcn_sched_barrier(0); } while (0)

__global__ __launch_bounds__(512, 2)
void gemm_mfma_kernel(const unsigned short* __restrict__ A,
                      const unsigned short* __restrict__ Bt,
                      const float* __restrict__ X,
                      unsigned short* __restrict__ Vb)
{
    __shared__ __align__(16) unsigned short As0[256 * 64];   // 32 KB each
    __shared__ __align__(16) unsigned short Bs0[256 * 64];
    __shared__ __align__(16) unsigned short As1[256 * 64];
    __shared__ __align__(16) unsigned short Bs1[256 * 64];
    int tid = threadIdx.x;
    int wv = tid >> 6, ln = tid & 63;
    int bid = blockIdx.x;
    int nbid = (bid & 7) * 32 + (bid >> 3);   // XCD-contiguous (256%8==0)
    int bm0 = (nbid >> 2) * 256;              // 64 m-tiles
    int bn0 = (nbid & 3) * 256;               // 4 n-tiles
    int wr = wv >> 2, wc = wv & 3;            // 2x4 wave grid

    // load i covers quarter i (rows i*64..i*64+63) of the 256-row panel
    const unsigned short* ga[4];
    const unsigned short* gb[4];
    int ldo[4];
    #pragma unroll
    for (int i = 0; i < 4; ++i) {
        int dci = i * 512 + wv * 64 + ln;     // dest chunk index (16B units)
        int row = dci >> 3, ch = dci & 7;
        int sc = ch ^ (row & 7);
        ga[i] = A  + (size_t)(bm0 + row) * 1024 + sc * 8;
        gb[i] = Bt + (size_t)(bn0 + row) * 1024 + sc * 8;
        ldo[i] = dci * 8;                      // u16 offset, linear dest
    }

    f32x4 acc[8][4] = {};
    int la = wr * 128 + (ln & 15);
    int lb = wc * 64 + (ln & 15);
    int kg = ln >> 4;                          // 0..3

#define READ_BFR(RB)                                                          \
    _Pragma("unroll")                                                         \
    for (int n = 0; n < 4; ++n)                                               \
      _Pragma("unroll")                                                       \
      for (int ks = 0; ks < 2; ++ks) {                                        \
        int row = lb + n * 16;                                                \
        bfr[n][ks] = *(const bf16x8*)&RB[row * 64 +                           \
                        (((kg + ks * 4) ^ (row & 7)) * 8)];                   \
      }

#define READ_AF(RA, MQ)                                                       \
    _Pragma("unroll")                                                         \
    for (int mm = 0; mm < 2; ++mm)                                            \
      _Pragma("unroll")                                                       \
      for (int ks = 0; ks < 2; ++ks) {                                        \
        int row = la + ((MQ) * 2 + mm) * 16;                                  \
        af[mm][ks] = *(const bf16x8*)&RA[row * 64 +                           \
                        (((kg + ks * 4) ^ (row & 7)) * 8)];                   \
      }

#define MFMAQ(MQ)                                                             \
    __builtin_amdgcn_s_setprio(1);                                            \
    _Pragma("unroll")                                                         \
    for (int mm = 0; mm < 2; ++mm)                                            \
      _Pragma("unroll")                                                       \
      for (int n = 0; n < 4; ++n)                                             \
        _Pragma("unroll")                                                     \
        for (int ks = 0; ks < 2; ++ks)                                        \
          acc[(MQ) * 2 + mm][n] = __builtin_amdgcn_mfma_f32_16x16x32_bf16(    \
              af[mm][ks], bfr[n][ks], acc[(MQ) * 2 + mm][n], 0, 0, 0);        \
    __builtin_amdgcn_s_setprio(0);

    // prologue: stage tile 0 -> buf0 in first-use order
    gload_lds16(gb[0], Bs0 + ldo[0]);
    gload_lds16(gb[1], Bs0 + ldo[1]);
    gload_lds16(gb[2], Bs0 + ldo[2]);
    gload_lds16(gb[3], Bs0 + ldo[3]);
    gload_lds16(ga[0], As0 + ldo[0]);
    gload_lds16(ga[2], As0 + ldo[2]);
    gload_lds16(ga[1], As0 + ldo[1]);
    gload_lds16(ga[3], As0 + ldo[3]);
    WAITV2(); BAR();   // B + even-A published; odd-A (2) still in flight

    unsigned short* Ac = As0; unsigned short* Bc = Bs0;
    unsigned short* An = As1; unsigned short* Bn = Bs1;
    for (int t = 0; t < 16; ++t) {
        int ktn = (t + 1) * 64;
        bool last = (t == 15);
        bf16x8 bfr[4][2], af[2][2];
        // ---- phase 0: bfr + af-q0 (even A-quarter); stage gb'[0..1] ----
        READ_BFR(Bc); READ_AF(Ac, 0);
        if (!last) { gload_lds16(gb[0] + ktn, Bn + ldo[0]);
                     gload_lds16(gb[1] + ktn, Bn + ldo[1]); }
        BAR(); LGK0();
        MFMAQ(0);
        BAR();
        // ---- phase 1: af-q1 (even A-quarter); stage gb'[2..3];
        //      then ensure this tile's odd A-quarters landed ----
        READ_AF(Ac, 1);
        if (!last) { gload_lds16(gb[2] + ktn, Bn + ldo[2]);
                     gload_lds16(gb[3] + ktn, Bn + ldo[3]); }
        BAR(); LGK0();
        MFMAQ(1);
        if (last) { WAITV0(); } else { WAITV4(); }
        BAR();
        // ---- phase 2: af-q2 (odd A-quarter); stage ga'[0],ga'[2] ----
        READ_AF(Ac, 2);
        if (!last) { gload_lds16(ga[0] + ktn, An + ldo[0]);
                     gload_lds16(ga[2] + ktn, An + ldo[2]); }
        BAR(); LGK0();
        MFMAQ(2);
        BAR();
        // ---- phase 3: af-q3 (odd A-quarter); stage ga'[1],ga'[3];
        //      then ensure next tile's B + even-A landed ----
        READ_AF(Ac, 3);
        if (!last) { gload_lds16(ga[1] + ktn, An + ldo[1]);
                     gload_lds16(ga[3] + ktn, An + ldo[3]); }
        BAR(); LGK0();
        MFMAQ(3);
        if (!last) WAITV2();
        BAR();
        // swap buffers
        unsigned short* tA = Ac; Ac = An; An = tA;
        unsigned short* tB = Bc; Bc = Bn; Bn = tB;
    }
#undef READ_BFR
#undef READ_AF
#undef MFMAQ

    // epilogue: v = acc + X, store bf16
    int rb0 = bm0 + wr * 128 + (ln >> 4) * 4;
    int cb0 = bn0 + wc * 64 + (ln & 15);
    #pragma unroll
    for (int m = 0; m < 8; ++m) {
        #pragma unroll
        for (int r = 0; r < 4; ++r) {
            int row = rb0 + m * 16 + r;
            size_t off = (size_t)row * 1024 + cb0;
            #pragma unroll
            for (int n = 0; n < 4; ++n)
                Vb[off + n * 16] = f2bf(acc[m][n][r] + X[off + n * 16]);
        }
    }
}

// ---------------- LayerNorm from bf16 V (row reduce + apply) ---------------
__global__ __launch_bounds__(256)
void ln_kernel(const unsigned short* __restrict__ Vb,
               const float* __restrict__ gamma,
               const float* __restrict__ beta,
               float* __restrict__ out) {
    __shared__ float red[8];
    int row = blockIdx.x;
    int tid = threadIdx.x;
    ushort4 vu = *(const ushort4*)&Vb[(size_t)row * 1024 + tid * 4];
    float v0 = bf2f(vu.x), v1 = bf2f(vu.y), v2 = bf2f(vu.z), v3 = bf2f(vu.w);
    float s = v0 + v1 + v2 + v3;
    float s2 = v0 * v0 + v1 * v1 + v2 * v2 + v3 * v3;
    #pragma unroll
    for (int off = 32; off; off >>= 1) {
        s  += __shfl_xor(s, off, 64);
        s2 += __shfl_xor(s2, off, 64);
    }
    if ((tid & 63) == 0) { red[(tid >> 6) * 2] = s; red[(tid >> 6) * 2 + 1] = s2; }
    __syncthreads();
    s  = red[0] + red[2] + red[4] + red[6];
    s2 = red[1] + red[3] + red[5] + red[7];
    float mu = s * (1.f / 1024.f);
    float var = s2 * (1.f / 1024.f) - mu * mu;
    float rs = rsqrtf(var + 1e-6f);
    float4 g  = *(const float4*)&gamma[tid * 4];
    float4 be = *(const float4*)&beta[tid * 4];
    float4 o = make_float4((v0 - mu) * rs * g.x + be.x,
                           (v1 - mu) * rs * g.y + be.y,
                           (v2 - mu) * rs * g.z + be.z,
                           (v3 - mu) * rs * g.w + be.w);
    *(float4*)&out[(size_t)row * 1024 + tid * 4] = o;
}

extern "C" void kernel_launch(void* const* d_in, const int* in_sizes, int n_in,
                              void* d_out, int out_size, void* d_ws, size_t ws_size,
                              hipStream_t stream) {
    const float* x     = (const float*)d_in[0];
    const float* W_pe  = (const float*)d_in[1];
    const float* b_pe  = (const float*)d_in[2];
    const float* stt   = (const float*)d_in[3];
    const float* W_fc  = (const float*)d_in[4];
    const float* gamma = (const float*)d_in[5];
    const float* beta  = (const float*)d_in[6];
    float* out = (float*)d_out;

    char* ws = (char*)d_ws;
    unsigned short* Vb    = (unsigned short*)ws;                               // 32 MB
    unsigned short* avgT  = (unsigned short*)(ws + (size_t)32 * 1024 * 1024);  // 32.5 MB
    unsigned short* convb = (unsigned short*)(ws + (size_t)68 * 1024 * 1024);  // 32 MB
    unsigned short* wfcb  = (unsigned short*)(ws + (size_t)100 * 1024 * 1024); //  2 MB
    unsigned short* wpeT  = (unsigned short*)(ws + (size_t)102 * 1024 * 1024); //  9 KB
    float*          segs  = (float*)(ws + (size_t)103 * 1024 * 1024);          //  1 MB

    seg_sum_kernel<<<1024, 256, 0, stream>>>(x, segs);
    avg_kernel<<<1024, 256, 0, stream>>>(x, segs, avgT);
    cvt_kernel<<<1025, 256, 0, stream>>>(W_fc, wfcb, W_pe, wpeT);
    conv_kernel<<<4096, 256, 0, stream>>>(avgT, wpeT, b_pe, stt, convb);
    gemm_mfma_kernel<<<256, 512, 0, stream>>>(convb, wfcb, x, Vb);
    ln_kernel<<<16384, 256, 0, stream>>>(Vb, gamma, beta, out);
}

// Round 22
// 129.484 us; speedup vs baseline: 1.2047x; 1.0915x over previous
//
#include <hip/hip_runtime.h>
#include <math.h>

// Problem constants (B,L,D,H,K) = (8, 2048, 1024, 16, 31)
#define BB 8
#define LL 2048
#define DD 1024
#define HH 16
#define DH 64          // D/H
#define KK 31
#define NSEG 32
#define SEGLEN 64      // LL/NSEG

#define TLEN 64        // tokens per conv block
#define TROW 2080      // avgT row stride (u16): 32-zero prefix + 2048 tokens
#define TSTR2 112      // winT row stride (u16): 14 chunks of 16B
#define WBSTR2 104     // wband row stride (u16): 208B
#define WPESTR2 72     // wpeT row stride (u16): 144B
#define PCSS 64        // pcs row stride (u16): row-internal accesses only
#define AST 72         // avg LDS tile row stride (u16): 36 dw, uniform banks

typedef __attribute__((ext_vector_type(8))) short bf16x8;
typedef __attribute__((ext_vector_type(4))) float f32x4;
typedef __attribute__((ext_vector_type(8))) unsigned short u16x8;

__device__ __forceinline__ unsigned short f2bf(float f) {
    unsigned u = __float_as_uint(f);
    unsigned r = (u + 0x7fffu + ((u >> 16) & 1u)) >> 16;   // RNE
    return (unsigned short)r;
}
__device__ __forceinline__ float bf2f(unsigned short s) {
    return __uint_as_float(((unsigned)s) << 16);
}

__device__ __forceinline__ void gload_lds16(const void* g, void* l) {
    __builtin_amdgcn_global_load_lds(
        (const __attribute__((address_space(1))) void*)g,
        (__attribute__((address_space(3))) void*)l, 16, 0, 0);
}

// ---------------- Pass 1a: per-segment sums (for parallel cumsum) ----------
__global__ __launch_bounds__(256)
void seg_sum_kernel(const float* __restrict__ x, float* __restrict__ segsum) {
    int g = blockIdx.x * 256 + threadIdx.x;   // B*NSEG*D threads
    int d = g & (DD - 1);
    int s = (g >> 10) & (NSEG - 1);
    int b = g >> 15;
    const float* p = x + (size_t)(b * LL + s * SEGLEN) * DD + d;
    float acc = 0.f;
    #pragma unroll 8
    for (int i = 0; i < SEGLEN; ++i) acc += p[(size_t)i * DD];
    segsum[g] = acc;   // layout [b][s][d] == flat g
}

// ---- Pass 1b: running mean -> avgT; LDS-transposed coalesced stores -------
__global__ __launch_bounds__(256)
void avg_kernel(const float* __restrict__ x, const float* __restrict__ segsum,
                unsigned short* __restrict__ avgT) {
    __shared__ __align__(16) unsigned short tile[256 * AST];   // 36864 B
    int tid = threadIdx.x;
    int bid = blockIdx.x;
    int dq = bid & 3;              // d-quarter
    int s = (bid >> 2) & (NSEG - 1);
    int b = bid >> 7;
    int d = dq * 256 + tid;
    float run = 0.f;
    const float* ss = segsum + ((size_t)b << 15) + d;
    for (int s2 = 0; s2 < s; ++s2) run += ss[s2 << 10];
    const float* p = x + (size_t)(b * LL + s * SEGLEN) * DD + d;
    int t0 = s * SEGLEN;
    #pragma unroll
    for (int j = 0; j < 8; ++j) {
        u16x8 v;
        #pragma unroll
        for (int e = 0; e < 8; ++e) {
            int i = j * 8 + e;
            run += p[(size_t)i * DD];
            v[e] = f2bf(run / (float)(t0 + i + 1));
        }
        *(u16x8*)&tile[tid * AST + j * 8] = v;
    }
    if (s == 0) {   // zero the 32-token prefix of this thread's row
        unsigned short* rowt = avgT +
            ((size_t)(b * HH + (d >> 6)) * DH + (d & 63)) * TROW;
        u16x8 z = {};
        #pragma unroll
        for (int j = 0; j < 4; ++j) *(u16x8*)&rowt[j * 8] = z;
    }
    __syncthreads();
    // coalesced stores: 8 lanes emit 8 consecutive 16B chunks of one row
    #pragma unroll
    for (int j = 0; j < 8; ++j) {
        int idx = j * 256 + tid;
        int dl = idx >> 3, ch = idx & 7;
        int dd = dq * 256 + dl;
        u16x8 v = *(const u16x8*)&tile[dl * AST + ch * 8];
        unsigned short* q = avgT +
            ((size_t)(b * HH + (dd >> 6)) * DH + (dd & 63)) * TROW
            + 32 + t0 + ch * 8;
        *(u16x8*)q = v;
    }
}

// ------- Fused: pc = ci@W_pe+b_pe -> gated energy -> softmax -> local conv --
// Grid is XCD-swizzled by the mapping below (4096 % 8 == 0).
__global__ __launch_bounds__(256, 4)
void conv_kernel(const unsigned short* __restrict__ avgT,
                 const unsigned short* __restrict__ wpeT,
                 const float* __restrict__ b_pe, const float* __restrict__ stt,
                 unsigned short* __restrict__ conv) {
    __shared__ __align__(16) unsigned short pcs[64 * PCSS];     //  8192 B
    __shared__ __align__(16) unsigned short winT[64 * TSTR2];   // 14336 B
    __shared__ __align__(16) unsigned short wub[64 * WBSTR2];   // 13312 B

    int tid = threadIdx.x;
    int bidl = (blockIdx.x & 7) * 512 + (blockIdx.x >> 3);
    int tile = bidl & 31;
    int bh = bidl >> 5;
    int b = bh >> 4, h = bh & 15;
    int t0 = tile * TLEN;
    int wv = tid >> 6, ln = tid & 63;
    int g = ln >> 4, li = ln & 15;

    // ---- phase 0: async staging (all global_load_lds width 16) ----
    {
        const unsigned short* gT = avgT + (size_t)(b * HH + h) * DH * TROW;
        #pragma unroll
        for (int q = 0; q < 3; ++q) {
            int i = tid + q * 256;
            int d = i / 14, c = i - d * 14;
            gload_lds16(gT + (size_t)d * TROW + t0 + c * 8, winT + (i & ~63) * 8);
        }
        if (tid < 128) {
            int i = 768 + tid;
            int d = i / 14, c = i - d * 14;
            gload_lds16(gT + (size_t)d * TROW + t0 + c * 8, winT + (i & ~63) * 8);
        }
        #pragma unroll
        for (int q = 0; q < 2; ++q) {
            int i = tid + q * 256;
            gload_lds16(wpeT + i * 8, wub + (i & ~63) * 8);
        }
        if (tid < 64) {
            int i = 512 + tid;
            gload_lds16(wpeT + i * 8, wub + (i & ~63) * 8);
        }
    }
    __syncthreads();

    // ---- phase 1: pc = ci @ W_pe via MFMA (A gathered from winT cols) ----
    f32x4 pacc[4];
    {
        int q32 = 32 + wv * 16 + li;   // window col of this token
        bf16x8 a0, a1;
        #pragma unroll
        for (int e = 0; e < 8; ++e) {
            a0[e] = (short)winT[(g * 8 + e) * TSTR2 + q32];
            a1[e] = (short)winT[(32 + g * 8 + e) * TSTR2 + q32];
        }
        #pragma unroll
        for (int n = 0; n < 4; ++n) {
            int c = n * 16 + li;
            bf16x8 b0 = *(const bf16x8*)&wub[c * WPESTR2 + g * 8];
            bf16x8 b1 = *(const bf16x8*)&wub[c * WPESTR2 + 32 + g * 8];
            f32x4 z = {0.f, 0.f, 0.f, 0.f};
            z = __builtin_amdgcn_mfma_f32_16x16x32_bf16(a0, b0, z, 0, 0, 0);
            z = __builtin_amdgcn_mfma_f32_16x16x32_bf16(a1, b1, z, 0, 0, 0);
            pacc[n] = z;
        }
    }
    __syncthreads();   // wpeT reads done; wub becomes wband below

    {   // pcs writes + zero wband (overlay wpeT)
        #pragma unroll
        for (int n = 0; n < 4; ++n) {
            int c = n * 16 + li;
            float bp = (c < 2 * KK) ? b_pe[c] : 0.f;
            #pragma unroll
            for (int r = 0; r < 4; ++r)
                pcs[(wv * 16 + g * 4 + r) * PCSS + c] = f2bf(pacc[n][r] + bp);
        }
        for (int i = tid; i < 64 * WBSTR2 / 8; i += 256) {
            u16x8 z = {};
            *(u16x8*)&wub[i * 8] = z;
        }
    }
    __syncthreads();

    // ---- phase 3: softmax (no max-reduce; energies bounded) -> wband ----
    {
        int half = ln >> 5, k = ln & 31;
        int kc = (k < KK) ? k : 0;
        float sttk = stt[h * KK + kc];
        for (int it = 0; it < 8; ++it) {
            int tok = wv * 16 + it * 2 + half;
            float dyn  = bf2f(pcs[tok * PCSS + kc]);
            float gate = bf2f(pcs[tok * PCSS + KK + kc]);
            float e = 0.f;
            if (k < KK) e = __expf(sttk + dyn / (1.f + __expf(-gate)));
            float sum = e;
            #pragma unroll
            for (int off = 16; off; off >>= 1) sum += __shfl_xor(sum, off, 64);
            float wvl = e / sum;
            if (k < KK && t0 + tok + k >= KK - 1)
                wub[tok * WBSTR2 + tok + k + 2] = f2bf(wvl);
        }
    }
    __syncthreads();

    // ---- phase 4: conv = wband @ winT^T via MFMA (K = 96) ----
    {
        int row = wv * 16 + li;
        bf16x8 wa0 = *(const bf16x8*)&wub[row * WBSTR2 + g * 8];
        bf16x8 wa1 = *(const bf16x8*)&wub[row * WBSTR2 + 32 + g * 8];
        bf16x8 wa2 = *(const bf16x8*)&wub[row * WBSTR2 + 64 + g * 8];
        f32x4 cacc[4];
        #pragma unroll
        for (int n = 0; n < 4; ++n) {
            int c = n * 16 + li;
            bf16x8 b0 = *(const bf16x8*)&winT[c * TSTR2 + g * 8];
            bf16x8 b1 = *(const bf16x8*)&winT[c * TSTR2 + 32 + g * 8];
            bf16x8 b2 = *(const bf16x8*)&winT[c * TSTR2 + 64 + g * 8];
            f32x4 z = {0.f, 0.f, 0.f, 0.f};
            z = __builtin_amdgcn_mfma_f32_16x16x32_bf16(wa0, b0, z, 0, 0, 0);
            z = __builtin_amdgcn_mfma_f32_16x16x32_bf16(wa1, b1, z, 0, 0, 0);
            z = __builtin_amdgcn_mfma_f32_16x16x32_bf16(wa2, b2, z, 0, 0, 0);
            cacc[n] = z;
        }
        #pragma unroll
        for (int n = 0; n < 4; ++n)
            #pragma unroll
            for (int r = 0; r < 4; ++r)
                pcs[(wv * 16 + g * 4 + r) * PCSS + n * 16 + li] =
                    f2bf(cacc[n][r]);
    }
    __syncthreads();

    // ---- phase 5: coalesced store ----
    {
        int tok = tid >> 2, j0 = (tid & 3) * 16;
        u16x8 v0 = *(const u16x8*)&pcs[tok * PCSS + j0];
        u16x8 v1 = *(const u16x8*)&pcs[tok * PCSS + j0 + 8];
        unsigned short* o = conv + (size_t)(b * LL + t0 + tok) * DD + h * DH + j0;
        *(u16x8*)&o[0] = v0;
        *(u16x8*)&o[8] = v1;
    }
}

// ---- W_fc f32 -> bf16 cast (2MB) + wpeT prep (block 1024) -----------------
__global__ __launch_bounds__(256)
void cvt_kernel(const float* __restrict__ in, unsigned short* __restrict__ out,
                const float* __restrict__ W_pe, unsigned short* __restrict__ wpeT) {
    if (blockIdx.x == 1024) {
        for (int i = threadIdx.x; i < 64 * WPESTR2; i += 256) {
            int c = i / WPESTR2, d = i - c * WPESTR2;
            float v = (c < 2 * KK && d < 64) ? W_pe[d * (2 * KK) + c] : 0.f;
            wpeT[i] = f2bf(v);
        }
        return;
    }
    int i = (blockIdx.x * 256 + threadIdx.x) * 4;
    float4 v = *(const float4*)&in[i];
    ushort4 o;
    o.x = f2bf(v.x); o.y = f2bf(v.y); o.z = f2bf(v.z); o.w = f2bf(v.w);
    *(ushort4*)&out[i] = o;
}

// ---- v = conv @ W_fc^T + x : 256x256 tile, 8 waves, BK=64, XOR-swizzled
//      LDS, double-buffered, 4 phases/K-tile with COUNTED vmcnt matched to
//      first-use (r16 schedule, best measured). f32 X residual. -------------
#define WAITV0() do { asm volatile("s_waitcnt vmcnt(0)" ::: "memory"); \
                      __builtin_amdgcn_sched_barrier(0); } while (0)
#define WAITV2() do { asm volatile("s_waitcnt vmcnt(2)" ::: "memory"); \
                      __builtin_amdgcn_sched_barrier(0); } while (0)
#define WAITV4() do { asm volatile("s_waitcnt vmcnt(4)" ::: "memory"); \
                      __builtin_amdgcn_sched_barrier(0); } while (0)
#define LGK0()   do { asm volatile("s_waitcnt lgkmcnt(0)" ::: "memory"); \
                      __builtin_amdgcn_sched_barrier(0); } while (0)
#define BAR()    do { __builtin_amdgcn_sched_barrier(0); \
                      __builtin_amdgcn_s_barrier(); \
                      __builtin_amdgcn_sched_barrier(0); } while (0)

__global__ __launch_bounds__(512, 2)
void gemm_mfma_kernel(const unsigned short* __restrict__ A,
                      const unsigned short* __restrict__ Bt,
                      const float* __restrict__ X,
                      unsigned short* __restrict__ Vb)
{
    __shared__ __align__(16) unsigned short As0[256 * 64];   // 32 KB each
    __shared__ __align__(16) unsigned short Bs0[256 * 64];
    __shared__ __align__(16) unsigned short As1[256 * 64];
    __shared__ __align__(16) unsigned short Bs1[256 * 64];
    int tid = threadIdx.x;
    int wv = tid >> 6, ln = tid & 63;
    int bid = blockIdx.x;
    int nbid = (bid & 7) * 32 + (bid >> 3);   // XCD-contiguous (256%8==0)
    int bm0 = (nbid >> 2) * 256;              // 64 m-tiles
    int bn0 = (nbid & 3) * 256;               // 4 n-tiles
    int wr = wv >> 2, wc = wv & 3;            // 2x4 wave grid

    // load i covers quarter i (rows i*64..i*64+63) of the 256-row panel
    const unsigned short* ga[4];
    const unsigned short* gb[4];
    int ldo[4];
    #pragma unroll
    for (int i = 0; i < 4; ++i) {
        int dci = i * 512 + wv * 64 + ln;     // dest chunk index (16B units)
        int row = dci >> 3, ch = dci & 7;
        int sc = ch ^ (row & 7);
        ga[i] = A  + (size_t)(bm0 + row) * 1024 + sc * 8;
        gb[i] = Bt + (size_t)(bn0 + row) * 1024 + sc * 8;
        ldo[i] = dci * 8;                      // u16 offset, linear dest
    }

    f32x4 acc[8][4] = {};
    int la = wr * 128 + (ln & 15);
    int lb = wc * 64 + (ln & 15);
    int kg = ln >> 4;                          // 0..3

#define READ_BFR(RB)                                                          \
    _Pragma("unroll")                                                         \
    for (int n = 0; n < 4; ++n)                                               \
      _Pragma("unroll")                                                       \
      for (int ks = 0; ks < 2; ++ks) {                                        \
        int row = lb + n * 16;                                                \
        bfr[n][ks] = *(const bf16x8*)&RB[row * 64 +                           \
                        (((kg + ks * 4) ^ (row & 7)) * 8)];                   \
      }

#define READ_AF(RA, MQ)                                                       \
    _Pragma("unroll")                                                         \
    for (int mm = 0; mm < 2; ++mm)                                            \
      _Pragma("unroll")                                                       \
      for (int ks = 0; ks < 2; ++ks) {                                        \
        int row = la + ((MQ) * 2 + mm) * 16;                                  \
        af[mm][ks] = *(const bf16x8*)&RA[row * 64 +                           \
                        (((kg + ks * 4) ^ (row & 7)) * 8)];                   \
      }

#define MFMAQ(MQ)                                                             \
    __builtin_amdgcn_s_setprio(1);                                            \
    _Pragma("unroll")                                                         \
    for (int mm = 0; mm < 2; ++mm)                                            \
      _Pragma("unroll")                                                       \
      for (int n = 0; n < 4; ++n)                                             \
        _Pragma("unroll")                                                     \
        for (int ks = 0; ks < 2; ++ks)                                        \
          acc[(MQ) * 2 + mm][n] = __builtin_amdgcn_mfma_f32_16x16x32_bf16(    \
              af[mm][ks], bfr[n][ks], acc[(MQ) * 2 + mm][n], 0, 0, 0);        \
    __builtin_amdgcn_s_setprio(0);

    // prologue: stage tile 0 -> buf0 in first-use order
    gload_lds16(gb[0], Bs0 + ldo[0]);
    gload_lds16(gb[1], Bs0 + ldo[1]);
    gload_lds16(gb[2], Bs0 + ldo[2]);
    gload_lds16(gb[3], Bs0 + ldo[3]);
    gload_lds16(ga[0], As0 + ldo[0]);
    gload_lds16(ga[2], As0 + ldo[2]);
    gload_lds16(ga[1], As0 + ldo[1]);
    gload_lds16(ga[3], As0 + ldo[3]);
    WAITV2(); BAR();   // B + even-A published; odd-A (2) still in flight

    unsigned short* Ac = As0; unsigned short* Bc = Bs0;
    unsigned short* An = As1; unsigned short* Bn = Bs1;
    for (int t = 0; t < 16; ++t) {
        int ktn = (t + 1) * 64;
        bool last = (t == 15);
        bf16x8 bfr[4][2], af[2][2];
        // ---- phase 0: bfr + af-q0 (even A-quarter); stage gb'[0..1] ----
        READ_BFR(Bc); READ_AF(Ac, 0);
        if (!last) { gload_lds16(gb[0] + ktn, Bn + ldo[0]);
                     gload_lds16(gb[1] + ktn, Bn + ldo[1]); }
        BAR(); LGK0();
        MFMAQ(0);
        BAR();
        // ---- phase 1: af-q1 (even A-quarter); stage gb'[2..3];
        //      then ensure this tile's odd A-quarters landed ----
        READ_AF(Ac, 1);
        if (!last) { gload_lds16(gb[2] + ktn, Bn + ldo[2]);
                     gload_lds16(gb[3] + ktn, Bn + ldo[3]); }
        BAR(); LGK0();
        MFMAQ(1);
        if (last) { WAITV0(); } else { WAITV4(); }
        BAR();
        // ---- phase 2: af-q2 (odd A-quarter); stage ga'[0],ga'[2] ----
        READ_AF(Ac, 2);
        if (!last) { gload_lds16(ga[0] + ktn, An + ldo[0]);
                     gload_lds16(ga[2] + ktn, An + ldo[2]); }
        BAR(); LGK0();
        MFMAQ(2);
        BAR();
        // ---- phase 3: af-q3 (odd A-quarter); stage ga'[1],ga'[3];
        //      then ensure next tile's B + even-A landed ----
        READ_AF(Ac, 3);
        if (!last) { gload_lds16(ga[1] + ktn, An + ldo[1]);
                     gload_lds16(ga[3] + ktn, An + ldo[3]); }
        BAR(); LGK0();
        MFMAQ(3);
        if (!last) WAITV2();
        BAR();
        // swap buffers
        unsigned short* tA = Ac; Ac = An; An = tA;
        unsigned short* tB = Bc; Bc = Bn; Bn = tB;
    }
#undef READ_BFR
#undef READ_AF
#undef MFMAQ

    // epilogue: v = acc + X, store bf16
    int rb0 = bm0 + wr * 128 + (ln >> 4) * 4;
    int cb0 = bn0 + wc * 64 + (ln & 15);
    #pragma unroll
    for (int m = 0; m < 8; ++m) {
        #pragma unroll
        for (int r = 0; r < 4; ++r) {
            int row = rb0 + m * 16 + r;
            size_t off = (size_t)row * 1024 + cb0;
            #pragma unroll
            for (int n = 0; n < 4; ++n)
                Vb[off + n * 16] = f2bf(acc[m][n][r] + X[off + n * 16]);
        }
    }
}

// ---------------- LayerNorm from bf16 V (row reduce + apply) ---------------
__global__ __launch_bounds__(256)
void ln_kernel(const unsigned short* __restrict__ Vb,
               const float* __restrict__ gamma,
               const float* __restrict__ beta,
               float* __restrict__ out) {
    __shared__ float red[8];
    int row = blockIdx.x;
    int tid = threadIdx.x;
    ushort4 vu = *(const ushort4*)&Vb[(size_t)row * 1024 + tid * 4];
    float v0 = bf2f(vu.x), v1 = bf2f(vu.y), v2 = bf2f(vu.z), v3 = bf2f(vu.w);
    float s = v0 + v1 + v2 + v3;
    float s2 = v0 * v0 + v1 * v1 + v2 * v2 + v3 * v3;
    #pragma unroll
    for (int off = 32; off; off >>= 1) {
        s  += __shfl_xor(s, off, 64);
        s2 += __shfl_xor(s2, off, 64);
    }
    if ((tid & 63) == 0) { red[(tid >> 6) * 2] = s; red[(tid >> 6) * 2 + 1] = s2; }
    __syncthreads();
    s  = red[0] + red[2] + red[4] + red[6];
    s2 = red[1] + red[3] + red[5] + red[7];
    float mu = s * (1.f / 1024.f);
    float var = s2 * (1.f / 1024.f) - mu * mu;
    float rs = rsqrtf(var + 1e-6f);
    float4 g  = *(const float4*)&gamma[tid * 4];
    float4 be = *(const float4*)&beta[tid * 4];
    float4 o = make_float4((v0 - mu) * rs * g.x + be.x,
                           (v1 - mu) * rs * g.y + be.y,
                           (v2 - mu) * rs * g.z + be.z,
                           (v3 - mu) * rs * g.w + be.w);
    *(float4*)&out[(size_t)row * 1024 + tid * 4] = o;
}

extern "C" void kernel_launch(void* const* d_in, const int* in_sizes, int n_in,
                              void* d_out, int out_size, void* d_ws, size_t ws_size,
                              hipStream_t stream) {
    const float* x     = (const float*)d_in[0];
    const float* W_pe  = (const float*)d_in[1];
    const float* b_pe  = (const float*)d_in[2];
    const float* stt   = (const float*)d_in[3];
    const float* W_fc  = (const float*)d_in[4];
    const float* gamma = (const float*)d_in[5];
    const float* beta  = (const float*)d_in[6];
    float* out = (float*)d_out;

    char* ws = (char*)d_ws;
    unsigned short* Vb    = (unsigned short*)ws;                               // 32 MB
    unsigned short* avgT  = (unsigned short*)(ws + (size_t)32 * 1024 * 1024);  // 32.5 MB
    unsigned short* convb = (unsigned short*)(ws + (size_t)68 * 1024 * 1024);  // 32 MB
    unsigned short* wfcb  = (unsigned short*)(ws + (size_t)100 * 1024 * 1024); //  2 MB
    unsigned short* wpeT  = (unsigned short*)(ws + (size_t)102 * 1024 * 1024); //  9 KB
    float*          segs  = (float*)(ws + (size_t)103 * 1024 * 1024);          //  1 MB

    seg_sum_kernel<<<1024, 256, 0, stream>>>(x, segs);
    avg_kernel<<<1024, 256, 0, stream>>>(x, segs, avgT);
    cvt_kernel<<<1025, 256, 0, stream>>>(W_fc, wfcb, W_pe, wpeT);
    conv_kernel<<<4096, 256, 0, stream>>>(avgT, wpeT, b_pe, stt, convb);
    gemm_mfma_kernel<<<256, 512, 0, stream>>>(convb, wfcb, x, Vb);
    ln_kernel<<<16384, 256, 0, stream>>>(Vb, gamma, beta, out);
}

// Round 23
// 128.177 us; speedup vs baseline: 1.2170x; 1.0102x over previous
//
#include <hip/hip_runtime.h>
#include <math.h>

// Problem constants (B,L,D,H,K) = (8, 2048, 1024, 16, 31)
#define BB 8
#define LL 2048
#define DD 1024
#define HH 16
#define DH 64          // D/H
#define KK 31
#define NSEG 32
#define SEGLEN 64      // LL/NSEG

#define TLEN 64        // tokens per conv block
#define TROW 2080      // avgT row stride (u16): 32-zero prefix + 2048 tokens
#define TSTR2 112      // winT row stride (u16): 14 chunks of 16B
#define WBSTR2 104     // wband row stride (u16): 208B
#define WPESTR2 72     // wpeT row stride (u16): 144B
#define PCSS 64        // pcs row stride (u16): row-internal accesses only
#define AST 72         // avg LDS tile row stride (u16): 36 dw, uniform banks

typedef __attribute__((ext_vector_type(8))) short bf16x8;
typedef __attribute__((ext_vector_type(4))) float f32x4;
typedef __attribute__((ext_vector_type(8))) unsigned short u16x8;

__device__ __forceinline__ unsigned short f2bf(float f) {
    unsigned u = __float_as_uint(f);
    unsigned r = (u + 0x7fffu + ((u >> 16) & 1u)) >> 16;   // RNE
    return (unsigned short)r;
}
__device__ __forceinline__ float bf2f(unsigned short s) {
    return __uint_as_float(((unsigned)s) << 16);
}

__device__ __forceinline__ void gload_lds16(const void* g, void* l) {
    __builtin_amdgcn_global_load_lds(
        (const __attribute__((address_space(1))) void*)g,
        (__attribute__((address_space(3))) void*)l, 16, 0, 0);
}

// ---------------- Pass 1a: per-segment sums (for parallel cumsum) ----------
__global__ __launch_bounds__(256)
void seg_sum_kernel(const float* __restrict__ x, float* __restrict__ segsum) {
    int g = blockIdx.x * 256 + threadIdx.x;   // B*NSEG*D threads
    int d = g & (DD - 1);
    int s = (g >> 10) & (NSEG - 1);
    int b = g >> 15;
    const float* p = x + (size_t)(b * LL + s * SEGLEN) * DD + d;
    float acc = 0.f;
    #pragma unroll 8
    for (int i = 0; i < SEGLEN; ++i) acc += p[(size_t)i * DD];
    segsum[g] = acc;   // layout [b][s][d] == flat g
}

// ---- Pass 1b: running mean -> avgT; LDS-transposed coalesced stores -------
__global__ __launch_bounds__(256)
void avg_kernel(const float* __restrict__ x, const float* __restrict__ segsum,
                unsigned short* __restrict__ avgT) {
    __shared__ __align__(16) unsigned short tile[256 * AST];   // 36864 B
    int tid = threadIdx.x;
    int bid = blockIdx.x;
    int dq = bid & 3;              // d-quarter
    int s = (bid >> 2) & (NSEG - 1);
    int b = bid >> 7;
    int d = dq * 256 + tid;
    float run = 0.f;
    const float* ss = segsum + ((size_t)b << 15) + d;
    for (int s2 = 0; s2 < s; ++s2) run += ss[s2 << 10];
    const float* p = x + (size_t)(b * LL + s * SEGLEN) * DD + d;
    int t0 = s * SEGLEN;
    #pragma unroll
    for (int j = 0; j < 8; ++j) {
        u16x8 v;
        #pragma unroll
        for (int e = 0; e < 8; ++e) {
            int i = j * 8 + e;
            run += p[(size_t)i * DD];
            v[e] = f2bf(run / (float)(t0 + i + 1));
        }
        *(u16x8*)&tile[tid * AST + j * 8] = v;
    }
    if (s == 0) {   // zero the 32-token prefix of this thread's row
        unsigned short* rowt = avgT +
            ((size_t)(b * HH + (d >> 6)) * DH + (d & 63)) * TROW;
        u16x8 z = {};
        #pragma unroll
        for (int j = 0; j < 4; ++j) *(u16x8*)&rowt[j * 8] = z;
    }
    __syncthreads();
    // coalesced stores: 8 lanes emit 8 consecutive 16B chunks of one row
    #pragma unroll
    for (int j = 0; j < 8; ++j) {
        int idx = j * 256 + tid;
        int dl = idx >> 3, ch = idx & 7;
        int dd = dq * 256 + dl;
        u16x8 v = *(const u16x8*)&tile[dl * AST + ch * 8];
        unsigned short* q = avgT +
            ((size_t)(b * HH + (dd >> 6)) * DH + (dd & 63)) * TROW
            + 32 + t0 + ch * 8;
        *(u16x8*)q = v;
    }
}

// ------- Fused: pc = ci@W_pe+b_pe -> gated energy -> softmax -> local conv --
// Grid is XCD-swizzled by the mapping below (4096 % 8 == 0).
__global__ __launch_bounds__(256, 4)
void conv_kernel(const unsigned short* __restrict__ avgT,
                 const unsigned short* __restrict__ wpeT,
                 const float* __restrict__ b_pe, const float* __restrict__ stt,
                 unsigned short* __restrict__ conv) {
    __shared__ __align__(16) unsigned short pcs[64 * PCSS];     //  8192 B
    __shared__ __align__(16) unsigned short winT[64 * TSTR2];   // 14336 B
    __shared__ __align__(16) unsigned short wub[64 * WBSTR2];   // 13312 B

    int tid = threadIdx.x;
    int bidl = (blockIdx.x & 7) * 512 + (blockIdx.x >> 3);
    int tile = bidl & 31;
    int bh = bidl >> 5;
    int b = bh >> 4, h = bh & 15;
    int t0 = tile * TLEN;
    int wv = tid >> 6, ln = tid & 63;
    int g = ln >> 4, li = ln & 15;

    // ---- phase 0: async staging (all global_load_lds width 16) ----
    {
        const unsigned short* gT = avgT + (size_t)(b * HH + h) * DH * TROW;
        #pragma unroll
        for (int q = 0; q < 3; ++q) {
            int i = tid + q * 256;
            int d = i / 14, c = i - d * 14;
            gload_lds16(gT + (size_t)d * TROW + t0 + c * 8, winT + (i & ~63) * 8);
        }
        if (tid < 128) {
            int i = 768 + tid;
            int d = i / 14, c = i - d * 14;
            gload_lds16(gT + (size_t)d * TROW + t0 + c * 8, winT + (i & ~63) * 8);
        }
        #pragma unroll
        for (int q = 0; q < 2; ++q) {
            int i = tid + q * 256;
            gload_lds16(wpeT + i * 8, wub + (i & ~63) * 8);
        }
        if (tid < 64) {
            int i = 512 + tid;
            gload_lds16(wpeT + i * 8, wub + (i & ~63) * 8);
        }
    }
    __syncthreads();

    // ---- phase 1: pc = ci @ W_pe via MFMA (A gathered from winT cols) ----
    f32x4 pacc[4];
    {
        int q32 = 32 + wv * 16 + li;   // window col of this token
        bf16x8 a0, a1;
        #pragma unroll
        for (int e = 0; e < 8; ++e) {
            a0[e] = (short)winT[(g * 8 + e) * TSTR2 + q32];
            a1[e] = (short)winT[(32 + g * 8 + e) * TSTR2 + q32];
        }
        #pragma unroll
        for (int n = 0; n < 4; ++n) {
            int c = n * 16 + li;
            bf16x8 b0 = *(const bf16x8*)&wub[c * WPESTR2 + g * 8];
            bf16x8 b1 = *(const bf16x8*)&wub[c * WPESTR2 + 32 + g * 8];
            f32x4 z = {0.f, 0.f, 0.f, 0.f};
            z = __builtin_amdgcn_mfma_f32_16x16x32_bf16(a0, b0, z, 0, 0, 0);
            z = __builtin_amdgcn_mfma_f32_16x16x32_bf16(a1, b1, z, 0, 0, 0);
            pacc[n] = z;
        }
    }
    __syncthreads();   // wpeT reads done; wub becomes wband below

    {   // pcs writes + zero wband (overlay wpeT)
        #pragma unroll
        for (int n = 0; n < 4; ++n) {
            int c = n * 16 + li;
            float bp = (c < 2 * KK) ? b_pe[c] : 0.f;
            #pragma unroll
            for (int r = 0; r < 4; ++r)
                pcs[(wv * 16 + g * 4 + r) * PCSS + c] = f2bf(pacc[n][r] + bp);
        }
        for (int i = tid; i < 64 * WBSTR2 / 8; i += 256) {
            u16x8 z = {};
            *(u16x8*)&wub[i * 8] = z;
        }
    }
    __syncthreads();

    // ---- phase 3: softmax (no max-reduce; energies bounded) -> wband ----
    {
        int half = ln >> 5, k = ln & 31;
        int kc = (k < KK) ? k : 0;
        float sttk = stt[h * KK + kc];
        for (int it = 0; it < 8; ++it) {
            int tok = wv * 16 + it * 2 + half;
            float dyn  = bf2f(pcs[tok * PCSS + kc]);
            float gate = bf2f(pcs[tok * PCSS + KK + kc]);
            float e = 0.f;
            if (k < KK) e = __expf(sttk + dyn / (1.f + __expf(-gate)));
            float sum = e;
            #pragma unroll
            for (int off = 16; off; off >>= 1) sum += __shfl_xor(sum, off, 64);
            float wvl = e / sum;
            if (k < KK && t0 + tok + k >= KK - 1)
                wub[tok * WBSTR2 + tok + k + 2] = f2bf(wvl);
        }
    }
    __syncthreads();

    // ---- phase 4: conv = wband @ winT^T via MFMA (K = 96) ----
    {
        int row = wv * 16 + li;
        bf16x8 wa0 = *(const bf16x8*)&wub[row * WBSTR2 + g * 8];
        bf16x8 wa1 = *(const bf16x8*)&wub[row * WBSTR2 + 32 + g * 8];
        bf16x8 wa2 = *(const bf16x8*)&wub[row * WBSTR2 + 64 + g * 8];
        f32x4 cacc[4];
        #pragma unroll
        for (int n = 0; n < 4; ++n) {
            int c = n * 16 + li;
            bf16x8 b0 = *(const bf16x8*)&winT[c * TSTR2 + g * 8];
            bf16x8 b1 = *(const bf16x8*)&winT[c * TSTR2 + 32 + g * 8];
            bf16x8 b2 = *(const bf16x8*)&winT[c * TSTR2 + 64 + g * 8];
            f32x4 z = {0.f, 0.f, 0.f, 0.f};
            z = __builtin_amdgcn_mfma_f32_16x16x32_bf16(wa0, b0, z, 0, 0, 0);
            z = __builtin_amdgcn_mfma_f32_16x16x32_bf16(wa1, b1, z, 0, 0, 0);
            z = __builtin_amdgcn_mfma_f32_16x16x32_bf16(wa2, b2, z, 0, 0, 0);
            cacc[n] = z;
        }
        #pragma unroll
        for (int n = 0; n < 4; ++n)
            #pragma unroll
            for (int r = 0; r < 4; ++r)
                pcs[(wv * 16 + g * 4 + r) * PCSS + n * 16 + li] =
                    f2bf(cacc[n][r]);
    }
    __syncthreads();

    // ---- phase 5: coalesced store ----
    {
        int tok = tid >> 2, j0 = (tid & 3) * 16;
        u16x8 v0 = *(const u16x8*)&pcs[tok * PCSS + j0];
        u16x8 v1 = *(const u16x8*)&pcs[tok * PCSS + j0 + 8];
        unsigned short* o = conv + (size_t)(b * LL + t0 + tok) * DD + h * DH + j0;
        *(u16x8*)&o[0] = v0;
        *(u16x8*)&o[8] = v1;
    }
}

// ---- W_fc f32 -> bf16 cast (2MB) + wpeT prep (block 1024) -----------------
__global__ __launch_bounds__(256)
void cvt_kernel(const float* __restrict__ in, unsigned short* __restrict__ out,
                const float* __restrict__ W_pe, unsigned short* __restrict__ wpeT) {
    if (blockIdx.x == 1024) {
        for (int i = threadIdx.x; i < 64 * WPESTR2; i += 256) {
            int c = i / WPESTR2, d = i - c * WPESTR2;
            float v = (c < 2 * KK && d < 64) ? W_pe[d * (2 * KK) + c] : 0.f;
            wpeT[i] = f2bf(v);
        }
        return;
    }
    int i = (blockIdx.x * 256 + threadIdx.x) * 4;
    float4 v = *(const float4*)&in[i];
    ushort4 o;
    o.x = f2bf(v.x); o.y = f2bf(v.y); o.z = f2bf(v.z); o.w = f2bf(v.w);
    *(ushort4*)&out[i] = o;
}

// ---- v = conv @ W_fc^T + x : 256x256 tile, 8 waves, BK=64, XOR-swizzled
//      LDS, double-buffered, 4 phases/K-tile with COUNTED vmcnt matched to
//      first-use (r16 schedule, best measured). f32 X residual. -------------
#define WAITV0() do { asm volatile("s_waitcnt vmcnt(0)" ::: "memory"); \
                      __builtin_amdgcn_sched_barrier(0); } while (0)
#define WAITV2() do { asm volatile("s_waitcnt vmcnt(2)" ::: "memory"); \
                      __builtin_amdgcn_sched_barrier(0); } while (0)
#define WAITV4() do { asm volatile("s_waitcnt vmcnt(4)" ::: "memory"); \
                      __builtin_amdgcn_sched_barrier(0); } while (0)
#define LGK0()   do { asm volatile("s_waitcnt lgkmcnt(0)" ::: "memory"); \
                      __builtin_amdgcn_sched_barrier(0); } while (0)
#define BAR()    do { __builtin_amdgcn_sched_barrier(0); \
                      __builtin_amdgcn_s_barrier(); \
                      __builtin_amdgcn_sched_barrier(0); } while (0)

__global__ __launch_bounds__(512, 2)
void gemm_mfma_kernel(const unsigned short* __restrict__ A,
                      const unsigned short* __restrict__ Bt,
                      const float* __restrict__ X,
                      unsigned short* __restrict__ Vb)
{
    __shared__ __align__(16) unsigned short As0[256 * 64];   // 32 KB each
    __shared__ __align__(16) unsigned short Bs0[256 * 64];
    __shared__ __align__(16) unsigned short As1[256 * 64];
    __shared__ __align__(16) unsigned short Bs1[256 * 64];
    int tid = threadIdx.x;
    int wv = tid >> 6, ln = tid & 63;
    int bid = blockIdx.x;
    int nbid = (bid & 7) * 32 + (bid >> 3);   // XCD-contiguous (256%8==0)
    int bm0 = (nbid >> 2) * 256;              // 64 m-tiles
    int bn0 = (nbid & 3) * 256;               // 4 n-tiles
    int wr = wv >> 2, wc = wv & 3;            // 2x4 wave grid

    // load i covers quarter i (rows i*64..i*64+63) of the 256-row panel
    const unsigned short* ga[4];
    const unsigned short* gb[4];
    int ldo[4];
    #pragma unroll
    for (int i = 0; i < 4; ++i) {
        int dci = i * 512 + wv * 64 + ln;     // dest chunk index (16B units)
        int row = dci >> 3, ch = dci & 7;
        int sc = ch ^ (row & 7);
        ga[i] = A  + (size_t)(bm0 + row) * 1024 + sc * 8;
        gb[i] = Bt + (size_t)(bn0 + row) * 1024 + sc * 8;
        ldo[i] = dci * 8;                      // u16 offset, linear dest
    }

    f32x4 acc[8][4] = {};
    int la = wr * 128 + (ln & 15);
    int lb = wc * 64 + (ln & 15);
    int kg = ln >> 4;                          // 0..3

#define READ_BFR(RB)                                                          \
    _Pragma("unroll")                                                         \
    for (int n = 0; n < 4; ++n)                                               \
      _Pragma("unroll")                                                       \
      for (int ks = 0; ks < 2; ++ks) {                                        \
        int row = lb + n * 16;                                                \
        bfr[n][ks] = *(const bf16x8*)&RB[row * 64 +                           \
                        (((kg + ks * 4) ^ (row & 7)) * 8)];                   \
      }

#define READ_AF(RA, MQ)                                                       \
    _Pragma("unroll")                                                         \
    for (int mm = 0; mm < 2; ++mm)                                            \
      _Pragma("unroll")                                                       \
      for (int ks = 0; ks < 2; ++ks) {                                        \
        int row = la + ((MQ) * 2 + mm) * 16;                                  \
        af[mm][ks] = *(const bf16x8*)&RA[row * 64 +                           \
                        (((kg + ks * 4) ^ (row & 7)) * 8)];                   \
      }

#define MFMAQ(MQ)                                                             \
    __builtin_amdgcn_s_setprio(1);                                            \
    _Pragma("unroll")                                                         \
    for (int mm = 0; mm < 2; ++mm)                                            \
      _Pragma("unroll")                                                       \
      for (int n = 0; n < 4; ++n)                                             \
        _Pragma("unroll")                                                     \
        for (int ks = 0; ks < 2; ++ks)                                        \
          acc[(MQ) * 2 + mm][n] = __builtin_amdgcn_mfma_f32_16x16x32_bf16(    \
              af[mm][ks], bfr[n][ks], acc[(MQ) * 2 + mm][n], 0, 0, 0);        \
    __builtin_amdgcn_s_setprio(0);

    // prologue: stage tile 0 -> buf0 in first-use order
    gload_lds16(gb[0], Bs0 + ldo[0]);
    gload_lds16(gb[1], Bs0 + ldo[1]);
    gload_lds16(gb[2], Bs0 + ldo[2]);
    gload_lds16(gb[3], Bs0 + ldo[3]);
    gload_lds16(ga[0], As0 + ldo[0]);
    gload_lds16(ga[2], As0 + ldo[2]);
    gload_lds16(ga[1], As0 + ldo[1]);
    gload_lds16(ga[3], As0 + ldo[3]);
    WAITV2(); BAR();   // B + even-A published; odd-A (2) still in flight

    unsigned short* Ac = As0; unsigned short* Bc = Bs0;
    unsigned short* An = As1; unsigned short* Bn = Bs1;
    for (int t = 0; t < 16; ++t) {
        int ktn = (t + 1) * 64;
        bool last = (t == 15);
        bf16x8 bfr[4][2], af[2][2];
        // ---- phase 0: bfr + af-q0 (even A-quarter); stage gb'[0..1] ----
        READ_BFR(Bc); READ_AF(Ac, 0);
        if (!last) { gload_lds16(gb[0] + ktn, Bn + ldo[0]);
                     gload_lds16(gb[1] + ktn, Bn + ldo[1]); }
        BAR(); LGK0();
        MFMAQ(0);
        BAR();
        // ---- phase 1: af-q1 (even A-quarter); stage gb'[2..3];
        //      then ensure this tile's odd A-quarters landed ----
        READ_AF(Ac, 1);
        if (!last) { gload_lds16(gb[2] + ktn, Bn + ldo[2]);
                     gload_lds16(gb[3] + ktn, Bn + ldo[3]); }
        BAR(); LGK0();
        MFMAQ(1);
        if (last) { WAITV0(); } else { WAITV4(); }
        BAR();
        // ---- phase 2: af-q2 (odd A-quarter); stage ga'[0],ga'[2] ----
        READ_AF(Ac, 2);
        if (!last) { gload_lds16(ga[0] + ktn, An + ldo[0]);
                     gload_lds16(ga[2] + ktn, An + ldo[2]); }
        BAR(); LGK0();
        MFMAQ(2);
        BAR();
        // ---- phase 3: af-q3 (odd A-quarter); stage ga'[1],ga'[3];
        //      then ensure next tile's B + even-A landed ----
        READ_AF(Ac, 3);
        if (!last) { gload_lds16(ga[1] + ktn, An + ldo[1]);
                     gload_lds16(ga[3] + ktn, An + ldo[3]); }
        BAR(); LGK0();
        MFMAQ(3);
        if (!last) WAITV2();
        BAR();
        // swap buffers
        unsigned short* tA = Ac; Ac = An; An = tA;
        unsigned short* tB = Bc; Bc = Bn; Bn = tB;
    }
#undef READ_BFR
#undef READ_AF
#undef MFMAQ

    // epilogue: v = acc + X, store bf16
    int rb0 = bm0 + wr * 128 + (ln >> 4) * 4;
    int cb0 = bn0 + wc * 64 + (ln & 15);
    #pragma unroll
    for (int m = 0; m < 8; ++m) {
        #pragma unroll
        for (int r = 0; r < 4; ++r) {
            int row = rb0 + m * 16 + r;
            size_t off = (size_t)row * 1024 + cb0;
            #pragma unroll
            for (int n = 0; n < 4; ++n)
                Vb[off + n * 16] = f2bf(acc[m][n][r] + X[off + n * 16]);
        }
    }
}

// ---------------- LayerNorm from bf16 V (row reduce + apply) ---------------
__global__ __launch_bounds__(256)
void ln_kernel(const unsigned short* __restrict__ Vb,
               const float* __restrict__ gamma,
               const float* __restrict__ beta,
               float* __restrict__ out) {
    __shared__ float red[8];
    int row = blockIdx.x;
    int tid = threadIdx.x;
    ushort4 vu = *(const ushort4*)&Vb[(size_t)row * 1024 + tid * 4];
    float v0 = bf2f(vu.x), v1 = bf2f(vu.y), v2 = bf2f(vu.z), v3 = bf2f(vu.w);
    float s = v0 + v1 + v2 + v3;
    float s2 = v0 * v0 + v1 * v1 + v2 * v2 + v3 * v3;
    #pragma unroll
    for (int off = 32; off; off >>= 1) {
        s  += __shfl_xor(s, off, 64);
        s2 += __shfl_xor(s2, off, 64);
    }
    if ((tid & 63) == 0) { red[(tid >> 6) * 2] = s; red[(tid >> 6) * 2 + 1] = s2; }
    __syncthreads();
    s  = red[0] + red[2] + red[4] + red[6];
    s2 = red[1] + red[3] + red[5] + red[7];
    float mu = s * (1.f / 1024.f);
    float var = s2 * (1.f / 1024.f) - mu * mu;
    float rs = rsqrtf(var + 1e-6f);
    float4 g  = *(const float4*)&gamma[tid * 4];
    float4 be = *(const float4*)&beta[tid * 4];
    float4 o = make_float4((v0 - mu) * rs * g.x + be.x,
                           (v1 - mu) * rs * g.y + be.y,
                           (v2 - mu) * rs * g.z + be.z,
                           (v3 - mu) * rs * g.w + be.w);
    *(float4*)&out[(size_t)row * 1024 + tid * 4] = o;
}

extern "C" void kernel_launch(void* const* d_in, const int* in_sizes, int n_in,
                              void* d_out, int out_size, void* d_ws, size_t ws_size,
                              hipStream_t stream) {
    const float* x     = (const float*)d_in[0];
    const float* W_pe  = (const float*)d_in[1];
    const float* b_pe  = (const float*)d_in[2];
    const float* stt   = (const float*)d_in[3];
    const float* W_fc  = (const float*)d_in[4];
    const float* gamma = (const float*)d_in[5];
    const float* beta  = (const float*)d_in[6];
    float* out = (float*)d_out;

    char* ws = (char*)d_ws;
    unsigned short* Vb    = (unsigned short*)ws;                               // 32 MB
    unsigned short* avgT  = (unsigned short*)(ws + (size_t)32 * 1024 * 1024);  // 32.5 MB
    unsigned short* convb = (unsigned short*)(ws + (size_t)68 * 1024 * 1024);  // 32 MB
    unsigned short* wfcb  = (unsigned short*)(ws + (size_t)100 * 1024 * 1024); //  2 MB
    unsigned short* wpeT  = (unsigned short*)(ws + (size_t)102 * 1024 * 1024); //  9 KB
    float*          segs  = (float*)(ws + (size_t)103 * 1024 * 1024);          //  1 MB

    seg_sum_kernel<<<1024, 256, 0, stream>>>(x, segs);
    avg_kernel<<<1024, 256, 0, stream>>>(x, segs, avgT);
    cvt_kernel<<<1025, 256, 0, stream>>>(W_fc, wfcb, W_pe, wpeT);
    conv_kernel<<<4096, 256, 0, stream>>>(avgT, wpeT, b_pe, stt, convb);
    gemm_mfma_kernel<<<256, 512, 0, stream>>>(convb, wfcb, x, Vb);
    ln_kernel<<<16384, 256, 0, stream>>>(Vb, gamma, beta, out);
}